// Round 1
// baseline (939.496 us; speedup 1.0000x reference)
//
#include <hip/hip_runtime.h>
#include <math.h>

#define NN 50000
#define EE 800000
// D=128, H=4, C=32, ED=64

// ---------------- prep kernels ----------------
// wgq[kk][h*64+f] = sum_c Wq[kk][h*32+c] * We[f][h*32+c]   (128x256)
__global__ __launch_bounds__(256) void k_prep1(const float* __restrict__ Wq,
                                               const float* __restrict__ We,
                                               float* __restrict__ wgq) {
  int kk = blockIdx.x;          // 0..127
  int o  = threadIdx.x;         // 0..255
  int h = o >> 6, f = o & 63;
  float s = 0.f;
#pragma unroll
  for (int c = 0; c < 32; ++c)
    s += Wq[kk * 128 + h * 32 + c] * We[f * 128 + h * 32 + c];
  wgq[kk * 256 + o] = s;
}

__global__ __launch_bounds__(256) void k_prep2(const float* __restrict__ bq,
                                               const float* __restrict__ We,
                                               const float* __restrict__ Wbeta,
                                               float* __restrict__ bgq,
                                               float* __restrict__ wcomb) {
  int o = threadIdx.x; int h = o >> 6, f = o & 63;
  float s = 0.f;
#pragma unroll
  for (int c = 0; c < 32; ++c) s += bq[h * 32 + c] * We[f * 128 + h * 32 + c];
  bgq[o] = s;
  if (o < 128) {
    wcomb[o]       = Wbeta[o]       + Wbeta[256 + o];   // w_out
    wcomb[128 + o] = Wbeta[128 + o] - Wbeta[256 + o];   // w_xr
  }
}

// ---------------- fused node GEMM: [N,128] @ [128,768] ----------------
// y<8: matrices q,k,v,xr (2 col-blocks of 64 each); y>=8: gq (4 col-blocks)
__global__ __launch_bounds__(256) void k_lin(const float* __restrict__ x,
    const float* __restrict__ Wq, const float* __restrict__ bq,
    const float* __restrict__ Wk, const float* __restrict__ bk,
    const float* __restrict__ Wv, const float* __restrict__ bv,
    const float* __restrict__ Ws, const float* __restrict__ bs,
    const float* __restrict__ Wgq, const float* __restrict__ bgq,
    float* __restrict__ qf, float* __restrict__ kf, float* __restrict__ vf,
    float* __restrict__ xrf, float* __restrict__ gqf) {
  __shared__ float xs[64][129];
  __shared__ float Wt[128][64];
  int t = threadIdx.x;
  int rb = blockIdx.x * 64;
  int y = blockIdx.y;
  const float* Wp; const float* bp; float* outp; int ldw, ldo, colbase;
  if (y < 8) {
    ldw = 128; ldo = 128; colbase = (y & 1) * 64;
    int m = y >> 1;
    if (m == 0)      { Wp = Wq; bp = bq; outp = qf; }
    else if (m == 1) { Wp = Wk; bp = bk; outp = kf; }
    else if (m == 2) { Wp = Wv; bp = bv; outp = vf; }
    else             { Wp = Ws; bp = bs; outp = xrf; }
  } else {
    ldw = 256; ldo = 256; colbase = (y - 8) * 64; Wp = Wgq; bp = bgq; outp = gqf;
  }
  for (int i = t; i < 64 * 128; i += 256) {
    int r = i >> 7, kk = i & 127; int row = rb + r;
    xs[r][kk] = (row < NN) ? x[row * 128 + kk] : 0.0f;
  }
  for (int i = t; i < 128 * 64; i += 256) {
    int kk = i >> 6, c = i & 63;
    Wt[kk][c] = Wp[kk * ldw + colbase + c];
  }
  __syncthreads();
  int tx = t & 15, ty = t >> 4;
  float acc[4][4] = {{0.f}};
  for (int kk = 0; kk < 128; ++kk) {
    float xv0 = xs[4 * ty + 0][kk];
    float xv1 = xs[4 * ty + 1][kk];
    float xv2 = xs[4 * ty + 2][kk];
    float xv3 = xs[4 * ty + 3][kk];
    float4 wv = *(const float4*)&Wt[kk][4 * tx];
    acc[0][0] += xv0 * wv.x; acc[0][1] += xv0 * wv.y; acc[0][2] += xv0 * wv.z; acc[0][3] += xv0 * wv.w;
    acc[1][0] += xv1 * wv.x; acc[1][1] += xv1 * wv.y; acc[1][2] += xv1 * wv.z; acc[1][3] += xv1 * wv.w;
    acc[2][0] += xv2 * wv.x; acc[2][1] += xv2 * wv.y; acc[2][2] += xv2 * wv.z; acc[2][3] += xv2 * wv.w;
    acc[3][0] += xv3 * wv.x; acc[3][1] += xv3 * wv.y; acc[3][2] += xv3 * wv.z; acc[3][3] += xv3 * wv.w;
  }
  float b0 = bp[colbase + 4 * tx + 0];
  float b1 = bp[colbase + 4 * tx + 1];
  float b2 = bp[colbase + 4 * tx + 2];
  float b3 = bp[colbase + 4 * tx + 3];
#pragma unroll
  for (int ii = 0; ii < 4; ++ii) {
    int row = rb + 4 * ty + ii;
    if (row < NN) {
      float4 o;
      o.x = acc[ii][0] + b0; o.y = acc[ii][1] + b1;
      o.z = acc[ii][2] + b2; o.w = acc[ii][3] + b3;
      *(float4*)&outp[(size_t)row * ldo + colbase + 4 * tx] = o;
    }
  }
}

// ---------------- CSR build ----------------
__global__ __launch_bounds__(256) void k_hist(const int* __restrict__ ei, int* __restrict__ counts) {
  int i = blockIdx.x * 256 + threadIdx.x;
  if (i < EE) atomicAdd(&counts[ei[EE + i]], 1);
}

// single-block exclusive scan; counts -> cursors (in place), offsets[N+1]
__global__ __launch_bounds__(256) void k_scan(int* __restrict__ counts, int* __restrict__ offsets) {
  __shared__ int sb[256];
  __shared__ int s_carry;
  int t = threadIdx.x;
  if (t == 0) s_carry = 0;
  __syncthreads();
  for (int base = 0; base < NN; base += 256) {
    int idx = base + t;
    int v = (idx < NN) ? counts[idx] : 0;
    sb[t] = v;
    __syncthreads();
    for (int off = 1; off < 256; off <<= 1) {
      int xv = (t >= off) ? sb[t - off] : 0;
      __syncthreads();
      sb[t] += xv;
      __syncthreads();
    }
    int incl = sb[t];
    int carry = s_carry;
    int excl = carry + incl - v;
    if (idx < NN) { offsets[idx] = excl; counts[idx] = excl; }
    __syncthreads();
    if (t == 255) s_carry = carry + incl;
    __syncthreads();
  }
  if (t == 0) offsets[NN] = s_carry;
}

__global__ __launch_bounds__(256) void k_fill(const int* __restrict__ ei, int* __restrict__ cursors,
                                              int* __restrict__ eidx, int* __restrict__ ssrc) {
  int i = blockIdx.x * 256 + threadIdx.x;
  if (i < EE) {
    int d = ei[EE + i];
    int p = atomicAdd(&cursors[d], 1);
    eidx[p] = i;
    ssrc[p] = ei[i];
  }
}

// ---------------- fused attention + beta-gate + gelu + residual + LN ----------------
// one wave per destination node; 4 waves (4 dsts) per block
__global__ __launch_bounds__(256) void k_attn(
    const float* __restrict__ qf, const float* __restrict__ kf, const float* __restrict__ vf,
    const float* __restrict__ xrf, const float* __restrict__ gqf,
    const float* __restrict__ ea, const float* __restrict__ We,
    const int* __restrict__ offsets, const int* __restrict__ eidx, const int* __restrict__ ssrc,
    const float* __restrict__ x, const float* __restrict__ wcomb,
    const float* __restrict__ gamma, const float* __restrict__ beta_ln,
    float* __restrict__ out) {
  __shared__ float lds_agg[4][260];
  int t = threadIdx.x; int wv = t >> 6; int lane = t & 63;
  int n = blockIdx.x * 4 + wv;          // N = 50000 divisible by 4 -> always < N
  int h = lane >> 4;
  int c0 = lane * 2, c1 = c0 + 1;
  const float scale = 0.17677669529663687f;  // 1/sqrt(32)

  float2 qv = *(const float2*)&qf[(size_t)n * 128 + c0];
  float q0 = qv.x * scale, q1 = qv.y * scale;
  float g0 = gqf[(size_t)n * 256 +   0 + lane] * scale;
  float g1 = gqf[(size_t)n * 256 +  64 + lane] * scale;
  float g2 = gqf[(size_t)n * 256 + 128 + lane] * scale;
  float g3 = gqf[(size_t)n * 256 + 192 + lane] * scale;
  int js = offsets[n], je = offsets[n + 1];

  float m0 = -__builtin_inff(), m1 = m0, m2 = m0, m3 = m0;
  float l0 = 0.f, l1 = 0.f, l2 = 0.f, l3 = 0.f;
  float ag0 = 0.f, ag1 = 0.f, ag2 = 0.f, ag3 = 0.f;
  float acc0 = 0.f, acc1 = 0.f;

  for (int j = js; j < je; ++j) {
    int eid = eidx[j];
    int s = ssrc[j];
    float eav = ea[(size_t)eid * 64 + lane];
    float2 kv = *(const float2*)&kf[(size_t)s * 128 + c0];
    float2 vv = *(const float2*)&vf[(size_t)s * 128 + c0];
    float qk = q0 * kv.x + q1 * kv.y;
    float p0 = g0 * eav + ((h == 0) ? qk : 0.0f);
    float p1 = g1 * eav + ((h == 1) ? qk : 0.0f);
    float p2 = g2 * eav + ((h == 2) ? qk : 0.0f);
    float p3 = g3 * eav + ((h == 3) ? qk : 0.0f);
#pragma unroll
    for (int off = 32; off > 0; off >>= 1) {
      p0 += __shfl_xor(p0, off);
      p1 += __shfl_xor(p1, off);
      p2 += __shfl_xor(p2, off);
      p3 += __shfl_xor(p3, off);
    }
    // online softmax per head
    float nm0 = fmaxf(m0, p0); float sc0 = __expf(m0 - nm0); float a0 = __expf(p0 - nm0);
    l0 = l0 * sc0 + a0; ag0 = ag0 * sc0 + a0 * eav; m0 = nm0;
    float nm1 = fmaxf(m1, p1); float sc1 = __expf(m1 - nm1); float a1 = __expf(p1 - nm1);
    l1 = l1 * sc1 + a1; ag1 = ag1 * sc1 + a1 * eav; m1 = nm1;
    float nm2 = fmaxf(m2, p2); float sc2 = __expf(m2 - nm2); float a2 = __expf(p2 - nm2);
    l2 = l2 * sc2 + a2; ag2 = ag2 * sc2 + a2 * eav; m2 = nm2;
    float nm3 = fmaxf(m3, p3); float sc3 = __expf(m3 - nm3); float a3 = __expf(p3 - nm3);
    l3 = l3 * sc3 + a3; ag3 = ag3 * sc3 + a3 * eav; m3 = nm3;
    float scl = (h == 0) ? sc0 : ((h == 1) ? sc1 : ((h == 2) ? sc2 : sc3));
    float av  = (h == 0) ? a0  : ((h == 1) ? a1  : ((h == 2) ? a2  : a3));
    acc0 = acc0 * scl + av * vv.x;
    acc1 = acc1 * scl + av * vv.y;
  }

  // out_e via Agg @ We (per node): stash Agg in LDS (stride 65 -> conflict-free)
  lds_agg[wv][0 * 65 + lane] = ag0;
  lds_agg[wv][1 * 65 + lane] = ag1;
  lds_agg[wv][2 * 65 + lane] = ag2;
  lds_agg[wv][3 * 65 + lane] = ag3;
  __syncthreads();
  float oe0 = 0.f, oe1 = 0.f;
  for (int f = 0; f < 64; ++f) {
    float a = lds_agg[wv][h * 65 + f];
    float2 wef = *(const float2*)&We[f * 128 + c0];
    oe0 += a * wef.x; oe1 += a * wef.y;
  }
  float inv0 = (l0 > 0.f) ? 1.0f / l0 : 1.0f;
  float inv1 = (l1 > 0.f) ? 1.0f / l1 : 1.0f;
  float inv2 = (l2 > 0.f) ? 1.0f / l2 : 1.0f;
  float inv3 = (l3 > 0.f) ? 1.0f / l3 : 1.0f;
  float invh = (h == 0) ? inv0 : ((h == 1) ? inv1 : ((h == 2) ? inv2 : inv3));
  float o0 = (acc0 + oe0) * invh;
  float o1 = (acc1 + oe1) * invh;

  // beta gate
  float2 xrv = *(const float2*)&xrf[(size_t)n * 128 + c0];
  float bpart = o0 * wcomb[c0] + o1 * wcomb[c1] + xrv.x * wcomb[128 + c0] + xrv.y * wcomb[128 + c1];
#pragma unroll
  for (int off = 32; off > 0; off >>= 1) bpart += __shfl_xor(bpart, off);
  float b = 1.0f / (1.0f + __expf(-bpart));
  float r0 = b * xrv.x + (1.0f - b) * o0;
  float r1 = b * xrv.y + (1.0f - b) * o1;

  // gelu(exact) + residual
  float2 xv = *(const float2*)&x[(size_t)n * 128 + c0];
  float ge0 = 0.5f * r0 * (1.0f + erff(r0 * 0.70710678118654752f)) + xv.x;
  float ge1 = 0.5f * r1 * (1.0f + erff(r1 * 0.70710678118654752f)) + xv.y;

  // LayerNorm over 128 channels
  float s1 = ge0 + ge1;
  float s2 = ge0 * ge0 + ge1 * ge1;
#pragma unroll
  for (int off = 32; off > 0; off >>= 1) {
    s1 += __shfl_xor(s1, off);
    s2 += __shfl_xor(s2, off);
  }
  float mean = s1 * (1.0f / 128.0f);
  float var = s2 * (1.0f / 128.0f) - mean * mean;
  float rstd = rsqrtf(var + 1e-5f);
  float2 ov;
  ov.x = (ge0 - mean) * rstd * gamma[c0] + beta_ln[c0];
  ov.y = (ge1 - mean) * rstd * gamma[c1] + beta_ln[c1];
  *(float2*)&out[(size_t)n * 128 + c0] = ov;
}

// ---------------- launch ----------------
extern "C" void kernel_launch(void* const* d_in, const int* in_sizes, int n_in,
                              void* d_out, int out_size, void* d_ws, size_t ws_size,
                              hipStream_t stream) {
  const float* x   = (const float*)d_in[0];
  const int*   ei  = (const int*)d_in[1];
  const float* ea  = (const float*)d_in[2];
  const float* Wq  = (const float*)d_in[3];
  const float* bq  = (const float*)d_in[4];
  const float* Wk  = (const float*)d_in[5];
  const float* bk  = (const float*)d_in[6];
  const float* Wv  = (const float*)d_in[7];
  const float* bv  = (const float*)d_in[8];
  const float* We  = (const float*)d_in[9];
  const float* Wsk = (const float*)d_in[10];
  const float* bsk = (const float*)d_in[11];
  const float* Wb  = (const float*)d_in[12];
  const float* gamma = (const float*)d_in[13];
  const float* beta  = (const float*)d_in[14];
  float* out = (float*)d_out;

  float* ws  = (float*)d_ws;
  float* qf  = ws;
  float* kf  = qf  + (size_t)NN * 128;
  float* vf  = kf  + (size_t)NN * 128;
  float* xrf = vf  + (size_t)NN * 128;
  float* gqf = xrf + (size_t)NN * 128;
  float* wgq = gqf + (size_t)NN * 256;
  float* bgq = wgq + 128 * 256;
  float* wcomb = bgq + 256;
  int* counts  = (int*)(wcomb + 256);
  int* offsets = counts + NN;
  int* eidx    = offsets + NN + 1;
  int* ssrc    = eidx + EE;

  hipMemsetAsync(counts, 0, NN * sizeof(int), stream);
  k_prep1<<<128, 256, 0, stream>>>(Wq, We, wgq);
  k_prep2<<<1, 256, 0, stream>>>(bq, We, Wb, bgq, wcomb);
  k_lin<<<dim3(782, 12), 256, 0, stream>>>(x, Wq, bq, Wk, bk, Wv, bv, Wsk, bsk,
                                           wgq, bgq, qf, kf, vf, xrf, gqf);
  k_hist<<<3125, 256, 0, stream>>>(ei, counts);
  k_scan<<<1, 256, 0, stream>>>(counts, offsets);
  k_fill<<<3125, 256, 0, stream>>>(ei, counts, eidx, ssrc);
  k_attn<<<12500, 256, 0, stream>>>(qf, kf, vf, xrf, gqf, ea, We,
                                    offsets, eidx, ssrc, x, wcomb, gamma, beta, out);
}

// Round 2
// 441.241 us; speedup vs baseline: 2.1292x; 2.1292x over previous
//
#include <hip/hip_runtime.h>
#include <math.h>

#define NN 50000
#define EE 800000
// D=128, H=4, C=32, ED=64

typedef __bf16 bf16x8 __attribute__((ext_vector_type(8)));
typedef float f32x4 __attribute__((ext_vector_type(4)));
typedef unsigned short ushort_t;
typedef unsigned int uint_t;

__device__ inline ushort_t f2bf(float f) {
  uint_t u = __float_as_uint(f);
  uint_t r = (u + 0x7fffu + ((u >> 16) & 1u)) >> 16;
  return (ushort_t)r;
}

// ---------------- prep kernels ----------------
// wgq[kk][h*64+f] = sum_c Wq[kk][h*32+c] * We[f][h*32+c]   (128x256) f32
__global__ __launch_bounds__(256) void k_prep1(const float* __restrict__ Wq,
                                               const float* __restrict__ We,
                                               float* __restrict__ wgq) {
  int kk = blockIdx.x;          // 0..127
  int o  = threadIdx.x;         // 0..255
  int h = o >> 6, f = o & 63;
  float s = 0.f;
#pragma unroll
  for (int c = 0; c < 32; ++c)
    s += Wq[kk * 128 + h * 32 + c] * We[f * 128 + h * 32 + c];
  wgq[kk * 256 + o] = s;
}

__global__ __launch_bounds__(256) void k_prep2(const float* __restrict__ bq,
                                               const float* __restrict__ We,
                                               const float* __restrict__ Wbeta,
                                               float* __restrict__ bgq,
                                               float* __restrict__ wcomb) {
  int o = threadIdx.x; int h = o >> 6, f = o & 63;
  float s = 0.f;
#pragma unroll
  for (int c = 0; c < 32; ++c) s += bq[h * 32 + c] * We[f * 128 + h * 32 + c];
  bgq[o] = s;
  if (o < 128) {
    wcomb[o]       = Wbeta[o]       + Wbeta[256 + o];   // w_out
    wcomb[128 + o] = Wbeta[128 + o] - Wbeta[256 + o];   // w_xr
  }
}

// Build transposed concatenated bf16 weights Wbt[768][128] and bias bcat[768].
// Col map: [0,128)=q ; [128,384)= interleaved k/v: col 128+4p+{0,1,2,3} =
//   K_{2p},K_{2p+1},V_{2p},V_{2p+1} ; [384,512)=skip ; [512,768)=gq
__global__ __launch_bounds__(256) void k_prepw(
    const float* __restrict__ Wq, const float* __restrict__ Wk,
    const float* __restrict__ Wv, const float* __restrict__ Ws,
    const float* __restrict__ wgq,
    const float* __restrict__ bq, const float* __restrict__ bk,
    const float* __restrict__ bv, const float* __restrict__ bs,
    const float* __restrict__ bgq,
    ushort_t* __restrict__ Wbt, float* __restrict__ bcat) {
  int i = blockIdx.x * 256 + threadIdx.x;   // 0..98303
  int c = i >> 7, k = i & 127;
  float w;
  if (c < 128)      w = Wq[k * 128 + c];
  else if (c < 384) { int r = c - 128; int p = r >> 2; int q = r & 3; int ch = 2 * p + (q & 1);
                      w = (q < 2) ? Wk[k * 128 + ch] : Wv[k * 128 + ch]; }
  else if (c < 512) w = Ws[k * 128 + (c - 384)];
  else              w = wgq[k * 256 + (c - 512)];
  Wbt[(size_t)c * 128 + k] = f2bf(w);
  if (i < 768) {
    float b;
    if (i < 128)      b = bq[i];
    else if (i < 384) { int r = i - 128; int p = r >> 2; int q = r & 3; int ch = 2 * p + (q & 1);
                        b = (q < 2) ? bk[ch] : bv[ch]; }
    else if (i < 512) b = bs[i - 384];
    else              b = bgq[i - 512];
    bcat[i] = b;
  }
}

// ---------------- MFMA GEMM: nf[N,768] = x[N,128] @ Wcat[128,768] + bcat ----
__global__ __launch_bounds__(256) void k_mm(const float* __restrict__ x,
                                            const ushort_t* __restrict__ Wbt,
                                            const float* __restrict__ bcat,
                                            float* __restrict__ nf) {
  __shared__ ushort_t As[128 * 128];   // [row][k], XOR-swizzled, 32KB
  __shared__ ushort_t Bs[128 * 128];   // [col][k], XOR-swizzled, 32KB
  int t = threadIdx.x;
  int rb = blockIdx.x * 128;
  int cb = blockIdx.y * 128;

  // stage A: convert f32 -> bf16 on the fly
  for (int q = t; q < 2048; q += 256) {     // 2048 chunks of 8 elems
    int r = q >> 4, j = q & 15;
    int row = rb + r;
    float4 f0 = make_float4(0.f, 0.f, 0.f, 0.f), f1 = f0;
    if (row < NN) {
      const float4* xp = (const float4*)&x[(size_t)row * 128 + j * 8];
      f0 = xp[0]; f1 = xp[1];
    }
    uint_t u0 = (uint_t)f2bf(f0.x) | ((uint_t)f2bf(f0.y) << 16);
    uint_t u1 = (uint_t)f2bf(f0.z) | ((uint_t)f2bf(f0.w) << 16);
    uint_t u2 = (uint_t)f2bf(f1.x) | ((uint_t)f2bf(f1.y) << 16);
    uint_t u3 = (uint_t)f2bf(f1.z) | ((uint_t)f2bf(f1.w) << 16);
    int e = r * 128 + ((j * 8) ^ ((r & 7) << 3));
    *(uint4*)&As[e] = make_uint4(u0, u1, u2, u3);
  }
  // stage B (already bf16)
  for (int q = t; q < 2048; q += 256) {
    int c = q >> 4, j = q & 15;
    uint4 w = *(const uint4*)&Wbt[(size_t)(cb + c) * 128 + j * 8];
    int e = c * 128 + ((j * 8) ^ ((c & 7) << 3));
    *(uint4*)&Bs[e] = w;
  }
  __syncthreads();

  int lane = t & 63;
  int wv = t >> 6;
  int wr = wv >> 1, wc = wv & 1;     // wave tile 64x64
  int l15 = lane & 15, l4 = lane >> 4;

  f32x4 acc[4][4];
#pragma unroll
  for (int i = 0; i < 4; ++i)
#pragma unroll
    for (int j = 0; j < 4; ++j) acc[i][j] = (f32x4){0.f, 0.f, 0.f, 0.f};

#pragma unroll
  for (int ks = 0; ks < 4; ++ks) {
    int kb = ks * 32 + l4 * 8;
    bf16x8 af[4], bfr[4];
#pragma unroll
    for (int i = 0; i < 4; ++i) {
      int r = wr * 64 + i * 16 + l15;
      af[i] = *(const bf16x8*)&As[r * 128 + (kb ^ ((r & 7) << 3))];
    }
#pragma unroll
    for (int j = 0; j < 4; ++j) {
      int c = wc * 64 + j * 16 + l15;
      bfr[j] = *(const bf16x8*)&Bs[c * 128 + (kb ^ ((c & 7) << 3))];
    }
#pragma unroll
    for (int i = 0; i < 4; ++i)
#pragma unroll
      for (int j = 0; j < 4; ++j)
        acc[i][j] = __builtin_amdgcn_mfma_f32_16x16x32_bf16(af[i], bfr[j], acc[i][j], 0, 0, 0);
  }

  // epilogue: D row = l4*4+reg, col = l15
#pragma unroll
  for (int j = 0; j < 4; ++j) {
    int colg = cb + wc * 64 + j * 16 + l15;
    float bv = bcat[colg];
#pragma unroll
    for (int i = 0; i < 4; ++i) {
#pragma unroll
      for (int reg = 0; reg < 4; ++reg) {
        int grow = rb + wr * 64 + i * 16 + l4 * 4 + reg;
        if (grow < NN) nf[(size_t)grow * 768 + colg] = acc[i][j][reg] + bv;
      }
    }
  }
}

// ---------------- CSR build ----------------
__global__ __launch_bounds__(256) void k_hist(const int* __restrict__ ei, int* __restrict__ counts) {
  int i = blockIdx.x * 256 + threadIdx.x;
  if (i < EE) atomicAdd(&counts[ei[EE + i]], 1);
}

// single-block scan, 1024 threads, shfl-based
__global__ __launch_bounds__(1024) void k_scan(int* __restrict__ counts, int* __restrict__ offsets) {
  __shared__ int wsum[16];
  __shared__ int s_carry;
  int t = threadIdx.x, lane = t & 63, w = t >> 6;
  if (t == 0) s_carry = 0;
  __syncthreads();
  for (int base = 0; base < NN; base += 1024) {
    int idx = base + t;
    int v = (idx < NN) ? counts[idx] : 0;
    int s = v;
#pragma unroll
    for (int off = 1; off < 64; off <<= 1) {
      int u = __shfl_up(s, off);
      if (lane >= off) s += u;
    }
    if (lane == 63) wsum[w] = s;
    __syncthreads();
    if (t == 0) {
      int ex = s_carry;
#pragma unroll
      for (int i = 0; i < 16; ++i) { int tv = wsum[i]; wsum[i] = ex; ex += tv; }
      s_carry = ex;
    }
    __syncthreads();
    int excl = wsum[w] + s - v;
    if (idx < NN) { offsets[idx] = excl; counts[idx] = excl; }
    __syncthreads();
  }
  if (threadIdx.x == 0) offsets[NN] = s_carry;
}

__global__ __launch_bounds__(256) void k_fill(const int* __restrict__ ei, int* __restrict__ cursors,
                                              int2* __restrict__ pairs) {
  int i = blockIdx.x * 256 + threadIdx.x;
  if (i < EE) {
    int d = ei[EE + i];
    int p = atomicAdd(&cursors[d], 1);
    pairs[p] = make_int2(i, ei[i]);
  }
}

// ---------------- fused attention + beta-gate + gelu + residual + LN --------
// one wave per destination node; lane(h=lane>>4, m=lane&15) owns:
//   q/k/v channels c0=2*lane,c0+1 ; ea & ag channels 4m..4m+3 of head h
__global__ __launch_bounds__(256) void k_attn(
    const float* __restrict__ nf, const float* __restrict__ ea,
    const float* __restrict__ We, const int* __restrict__ offsets,
    const int2* __restrict__ pairs, const float* __restrict__ x,
    const float* __restrict__ wcomb, const float* __restrict__ gamma,
    const float* __restrict__ beta_ln, float* __restrict__ out) {
  __shared__ float lds_agg[4][292];
  int t = threadIdx.x, wv = t >> 6, lane = t & 63;
  int n = blockIdx.x * 4 + wv;           // N divisible by 4
  int h = lane >> 4, m = lane & 15;
  int c0 = lane * 2, c1 = c0 + 1;
  const float scale = 0.17677669529663687f;   // 1/sqrt(32)

  const float* nrow = nf + (size_t)n * 768;
  float2 qv = *(const float2*)&nrow[c0];
  float q0 = qv.x * scale, q1 = qv.y * scale;
  float4 g4 = *(const float4*)&nrow[512 + h * 64 + 4 * m];
  g4.x *= scale; g4.y *= scale; g4.z *= scale; g4.w *= scale;

  int js = offsets[n], je = offsets[n + 1];
  float l = 0.f, acc0 = 0.f, acc1 = 0.f;
  float4 ag = make_float4(0.f, 0.f, 0.f, 0.f);

  for (int base = js; base < je; base += 64) {
    int nj = je - base; if (nj > 64) nj = 64;
    int2 pr = (lane < nj) ? pairs[base + lane] : make_int2(0, 0);
    for (int j = 0; j < nj; ++j) {
      int eid = __builtin_amdgcn_readlane(pr.x, j);
      int s   = __builtin_amdgcn_readlane(pr.y, j);
      float4 ev = *(const float4*)&ea[(size_t)eid * 64 + 4 * m];
      float4 kv = *(const float4*)&nf[(size_t)s * 768 + 128 + 4 * lane]; // k0,k1,v0,v1
      float p = q0 * kv.x + q1 * kv.y
              + g4.x * ev.x + g4.y * ev.y + g4.z * ev.z + g4.w * ev.w;
      p += __shfl_xor(p, 1); p += __shfl_xor(p, 2);
      p += __shfl_xor(p, 4); p += __shfl_xor(p, 8);   // sum within 16-lane head group
      float a = __expf(p);          // no max-subtraction: alphas are O(1), safe in f32
      l += a;
      acc0 += a * kv.z; acc1 += a * kv.w;
      ag.x += a * ev.x; ag.y += a * ev.y; ag.z += a * ev.z; ag.w += a * ev.w;
    }
  }

  // out_e = (Agg @ We) at this lane's channels
  *(float4*)&lds_agg[wv][h * 72 + 4 * m] = ag;
  __syncthreads();
  float oe0 = 0.f, oe1 = 0.f;
  const float* ap = &lds_agg[wv][h * 72];
#pragma unroll 4
  for (int f = 0; f < 64; ++f) {
    float a = ap[f];
    float2 w2 = *(const float2*)&We[f * 128 + c0];
    oe0 += a * w2.x; oe1 += a * w2.y;
  }
  float inv = (l > 0.f) ? (1.0f / l) : 1.0f;
  float o0 = (acc0 + oe0) * inv;
  float o1 = (acc1 + oe1) * inv;

  // beta gate
  float2 xrv = *(const float2*)&nrow[384 + c0];
  float bp = o0 * wcomb[c0] + o1 * wcomb[c1] + xrv.x * wcomb[128 + c0] + xrv.y * wcomb[128 + c1];
#pragma unroll
  for (int off = 32; off > 0; off >>= 1) bp += __shfl_xor(bp, off);
  float bgate = 1.0f / (1.0f + __expf(-bp));
  float r0 = bgate * xrv.x + (1.0f - bgate) * o0;
  float r1 = bgate * xrv.y + (1.0f - bgate) * o1;

  // gelu(exact) + residual
  float2 xv = *(const float2*)&x[(size_t)n * 128 + c0];
  float ge0 = 0.5f * r0 * (1.0f + erff(r0 * 0.70710678118654752f)) + xv.x;
  float ge1 = 0.5f * r1 * (1.0f + erff(r1 * 0.70710678118654752f)) + xv.y;

  // LayerNorm over 128 channels
  float s1 = ge0 + ge1;
  float s2 = ge0 * ge0 + ge1 * ge1;
#pragma unroll
  for (int off = 32; off > 0; off >>= 1) {
    s1 += __shfl_xor(s1, off);
    s2 += __shfl_xor(s2, off);
  }
  float mean = s1 * (1.0f / 128.0f);
  float var = s2 * (1.0f / 128.0f) - mean * mean;
  float rstd = rsqrtf(var + 1e-5f);
  float2 ov;
  ov.x = (ge0 - mean) * rstd * gamma[c0] + beta_ln[c0];
  ov.y = (ge1 - mean) * rstd * gamma[c1] + beta_ln[c1];
  *(float2*)&out[(size_t)n * 128 + c0] = ov;
}

// ---------------- launch ----------------
extern "C" void kernel_launch(void* const* d_in, const int* in_sizes, int n_in,
                              void* d_out, int out_size, void* d_ws, size_t ws_size,
                              hipStream_t stream) {
  const float* x   = (const float*)d_in[0];
  const int*   ei  = (const int*)d_in[1];
  const float* ea  = (const float*)d_in[2];
  const float* Wq  = (const float*)d_in[3];
  const float* bq  = (const float*)d_in[4];
  const float* Wk  = (const float*)d_in[5];
  const float* bk  = (const float*)d_in[6];
  const float* Wv  = (const float*)d_in[7];
  const float* bv  = (const float*)d_in[8];
  const float* We  = (const float*)d_in[9];
  const float* Wsk = (const float*)d_in[10];
  const float* bsk = (const float*)d_in[11];
  const float* Wb  = (const float*)d_in[12];
  const float* gamma = (const float*)d_in[13];
  const float* beta  = (const float*)d_in[14];
  float* out = (float*)d_out;

  char* cur = (char*)d_ws;
  auto alloc = [&](size_t bytes) {
    void* p = (void*)cur;
    cur += (bytes + 255) & ~(size_t)255;
    return p;
  };
  float*    nf      = (float*)alloc((size_t)NN * 768 * 4);
  float*    wgq     = (float*)alloc(128 * 256 * 4);
  float*    bgq     = (float*)alloc(256 * 4);
  float*    wcomb   = (float*)alloc(256 * 4);
  float*    bcat    = (float*)alloc(768 * 4);
  ushort_t* Wbt     = (ushort_t*)alloc((size_t)768 * 128 * 2);
  int*      counts  = (int*)alloc((size_t)NN * 4);
  int*      offsets = (int*)alloc((size_t)(NN + 1) * 4);
  int2*     pairs   = (int2*)alloc((size_t)EE * 8);

  hipMemsetAsync(counts, 0, NN * sizeof(int), stream);
  k_prep1<<<128, 256, 0, stream>>>(Wq, We, wgq);
  k_prep2<<<1, 256, 0, stream>>>(bq, We, Wb, bgq, wcomb);
  k_prepw<<<384, 256, 0, stream>>>(Wq, Wk, Wv, Wsk, wgq, bq, bk, bv, bsk, bgq, Wbt, bcat);
  k_mm<<<dim3(391, 6), 256, 0, stream>>>(x, Wbt, bcat, nf);
  k_hist<<<3125, 256, 0, stream>>>(ei, counts);
  k_scan<<<1, 1024, 0, stream>>>(counts, offsets);
  k_fill<<<3125, 256, 0, stream>>>(ei, counts, pairs);
  k_attn<<<12500, 256, 0, stream>>>(nf, ea, We, offsets, pairs, x, wcomb, gamma, beta, out);
}

// Round 3
// 393.341 us; speedup vs baseline: 2.3885x; 1.1218x over previous
//
#include <hip/hip_runtime.h>
#include <math.h>

#define NN 50000
#define EE 800000
// D=128, H=4, C=32, ED=64

typedef __bf16 bf16x8 __attribute__((ext_vector_type(8)));
typedef float f32x4 __attribute__((ext_vector_type(4)));
typedef unsigned short ushort_t;
typedef unsigned int uint_t;

__device__ inline ushort_t f2bf(float f) {
  uint_t u = __float_as_uint(f);
  uint_t r = (u + 0x7fffu + ((u >> 16) & 1u)) >> 16;
  return (ushort_t)r;
}
__device__ inline float bflo(uint_t u) { return __uint_as_float(u << 16); }
__device__ inline float bfhi(uint_t u) { return __uint_as_float(u & 0xffff0000u); }

// ---------------- prepA: wgq (128 blocks) + prep2 (1 block) + zero counts ----
__global__ __launch_bounds__(256) void k_prepA(const float* __restrict__ Wq,
                                               const float* __restrict__ We,
                                               const float* __restrict__ bq,
                                               const float* __restrict__ Wbeta,
                                               float* __restrict__ wgq,
                                               float* __restrict__ bgq,
                                               float* __restrict__ wcomb,
                                               int* __restrict__ counts) {
  int b = blockIdx.x;
  int o = threadIdx.x;
  if (b < 128) {
    int kk = b, h = o >> 6, f = o & 63;
    float s = 0.f;
#pragma unroll
    for (int c = 0; c < 32; ++c)
      s += Wq[kk * 128 + h * 32 + c] * We[f * 128 + h * 32 + c];
    wgq[kk * 256 + o] = s;
  } else if (b == 128) {
    int h = o >> 6, f = o & 63;
    float s = 0.f;
#pragma unroll
    for (int c = 0; c < 32; ++c) s += bq[h * 32 + c] * We[f * 128 + h * 32 + c];
    bgq[o] = s;
    if (o < 128) {
      wcomb[o]       = Wbeta[o]       + Wbeta[256 + o];
      wcomb[128 + o] = Wbeta[128 + o] - Wbeta[256 + o];
    }
  } else {
    int i = (b - 129) * 256 + o;
    if (i < NN) counts[i] = 0;
  }
}

// ---------------- prepB: build Wbt[768][128] bf16 + bcat (384 blocks) + hist -
// Col map: [0,128)=q ; [128,384)= interleaved k/v (col 128+4p+{0,1,2,3} =
//   K_{2p},K_{2p+1},V_{2p},V_{2p+1}) ; [384,512)=skip ; [512,768)=gq
__global__ __launch_bounds__(256) void k_prepB(
    const float* __restrict__ Wq, const float* __restrict__ Wk,
    const float* __restrict__ Wv, const float* __restrict__ Ws,
    const float* __restrict__ wgq,
    const float* __restrict__ bq, const float* __restrict__ bk,
    const float* __restrict__ bv, const float* __restrict__ bs,
    const float* __restrict__ bgq,
    ushort_t* __restrict__ Wbt, float* __restrict__ bcat,
    const int* __restrict__ ei, int* __restrict__ counts) {
  int b = blockIdx.x;
  if (b >= 384) {
    int i = (b - 384) * 256 + threadIdx.x;
    if (i < EE) atomicAdd(&counts[ei[EE + i]], 1);
    return;
  }
  int i = b * 256 + threadIdx.x;   // 0..98303
  int c = i >> 7, k = i & 127;
  float w;
  if (c < 128)      w = Wq[k * 128 + c];
  else if (c < 384) { int r = c - 128; int p = r >> 2; int q = r & 3; int ch = 2 * p + (q & 1);
                      w = (q < 2) ? Wk[k * 128 + ch] : Wv[k * 128 + ch]; }
  else if (c < 512) w = Ws[k * 128 + (c - 384)];
  else              w = wgq[k * 256 + (c - 512)];
  Wbt[(size_t)c * 128 + k] = f2bf(w);
  if (i < 768) {
    float bb;
    if (i < 128)      bb = bq[i];
    else if (i < 384) { int r = i - 128; int p = r >> 2; int q = r & 3; int ch = 2 * p + (q & 1);
                        bb = (q < 2) ? bk[ch] : bv[ch]; }
    else if (i < 512) bb = bs[i - 384];
    else              bb = bgq[i - 512];
    bcat[i] = bb;
  }
}

// ---------------- MFMA GEMM: [N,128] @ [128,768] + bias ---------------------
// col blocks: 0=q->nf[0:128), 1,2=kv->kvb bf16, 3=xr->nf[128:256), 4,5=g->nf[256:512)
__global__ __launch_bounds__(256) void k_mm(const float* __restrict__ x,
                                            const ushort_t* __restrict__ Wbt,
                                            const float* __restrict__ bcat,
                                            float* __restrict__ nf,
                                            ushort_t* __restrict__ kvb) {
  __shared__ ushort_t As[128 * 128];
  __shared__ ushort_t Bs[128 * 128];
  int t = threadIdx.x;
  int rb = blockIdx.x * 128;
  int cb = blockIdx.y * 128;

  for (int q = t; q < 2048; q += 256) {
    int r = q >> 4, j = q & 15;
    int row = rb + r;
    float4 f0 = make_float4(0.f, 0.f, 0.f, 0.f), f1 = f0;
    if (row < NN) {
      const float4* xp = (const float4*)&x[(size_t)row * 128 + j * 8];
      f0 = xp[0]; f1 = xp[1];
    }
    uint_t u0 = (uint_t)f2bf(f0.x) | ((uint_t)f2bf(f0.y) << 16);
    uint_t u1 = (uint_t)f2bf(f0.z) | ((uint_t)f2bf(f0.w) << 16);
    uint_t u2 = (uint_t)f2bf(f1.x) | ((uint_t)f2bf(f1.y) << 16);
    uint_t u3 = (uint_t)f2bf(f1.z) | ((uint_t)f2bf(f1.w) << 16);
    int e = r * 128 + ((j * 8) ^ ((r & 7) << 3));
    *(uint4*)&As[e] = make_uint4(u0, u1, u2, u3);
  }
  for (int q = t; q < 2048; q += 256) {
    int c = q >> 4, j = q & 15;
    uint4 w = *(const uint4*)&Wbt[(size_t)(cb + c) * 128 + j * 8];
    int e = c * 128 + ((j * 8) ^ ((c & 7) << 3));
    *(uint4*)&Bs[e] = w;
  }
  __syncthreads();

  int lane = t & 63;
  int wv = t >> 6;
  int wr = wv >> 1, wc = wv & 1;
  int l15 = lane & 15, l4 = lane >> 4;

  f32x4 acc[4][4];
#pragma unroll
  for (int i = 0; i < 4; ++i)
#pragma unroll
    for (int j = 0; j < 4; ++j) acc[i][j] = (f32x4){0.f, 0.f, 0.f, 0.f};

#pragma unroll
  for (int ks = 0; ks < 4; ++ks) {
    int kb = ks * 32 + l4 * 8;
    bf16x8 af[4], bfr[4];
#pragma unroll
    for (int i = 0; i < 4; ++i) {
      int r = wr * 64 + i * 16 + l15;
      af[i] = *(const bf16x8*)&As[r * 128 + (kb ^ ((r & 7) << 3))];
    }
#pragma unroll
    for (int j = 0; j < 4; ++j) {
      int c = wc * 64 + j * 16 + l15;
      bfr[j] = *(const bf16x8*)&Bs[c * 128 + (kb ^ ((c & 7) << 3))];
    }
#pragma unroll
    for (int i = 0; i < 4; ++i)
#pragma unroll
      for (int j = 0; j < 4; ++j)
        acc[i][j] = __builtin_amdgcn_mfma_f32_16x16x32_bf16(af[i], bfr[j], acc[i][j], 0, 0, 0);
  }

  bool iskv = (cb == 128 || cb == 256);
#pragma unroll
  for (int j = 0; j < 4; ++j) {
    int colg = cb + wc * 64 + j * 16 + l15;
    float bv = bcat[colg];
#pragma unroll
    for (int i = 0; i < 4; ++i) {
#pragma unroll
      for (int reg = 0; reg < 4; ++reg) {
        int grow = rb + wr * 64 + i * 16 + l4 * 4 + reg;
        if (grow < NN) {
          float val = acc[i][j][reg] + bv;
          if (iskv) kvb[(size_t)grow * 256 + (colg - 128)] = f2bf(val);
          else {
            int nc = (colg < 128) ? colg : colg - 256;
            nf[(size_t)grow * 512 + nc] = val;
          }
        }
      }
    }
  }
}

// ---------------- single-block scan, int4-vectorized ------------------------
__global__ __launch_bounds__(1024) void k_scan(int* __restrict__ counts, int* __restrict__ offsets) {
  __shared__ int wsum[16];
  __shared__ int s_carry;
  int4* counts4 = (int4*)counts;
  int4* offsets4 = (int4*)offsets;
  int t = threadIdx.x, lane = t & 63, w = t >> 6;
  if (t == 0) s_carry = 0;
  __syncthreads();
  for (int base = 0; base < 12500; base += 1024) {
    int idx = base + t;
    int4 v = (idx < 12500) ? counts4[idx] : make_int4(0, 0, 0, 0);
    int e1 = v.x, e2 = e1 + v.y, e3 = e2 + v.z, tot = e3 + v.w;
    int s = tot;
#pragma unroll
    for (int off = 1; off < 64; off <<= 1) {
      int u = __shfl_up(s, off);
      if (lane >= off) s += u;
    }
    if (lane == 63) wsum[w] = s;
    __syncthreads();
    if (t == 0) {
      int ex = s_carry;
#pragma unroll
      for (int i = 0; i < 16; ++i) { int tv = wsum[i]; wsum[i] = ex; ex += tv; }
      s_carry = ex;
    }
    __syncthreads();
    int be = wsum[w] + s - tot;
    if (idx < 12500) {
      int4 o = make_int4(be, be + e1, be + e2, be + e3);
      offsets4[idx] = o;
      counts4[idx] = o;
    }
    __syncthreads();
  }
  if (t == 0) offsets[NN] = s_carry;
}

__global__ __launch_bounds__(256) void k_fill(const int* __restrict__ ei, int* __restrict__ cursors,
                                              int2* __restrict__ pairs) {
  int i = blockIdx.x * 256 + threadIdx.x;
  if (i < EE) {
    int d = ei[EE + i];
    int p = atomicAdd(&cursors[d], 1);
    pairs[p] = make_int2(i, ei[i]);
  }
}

// ---------------- fused attention + beta-gate + gelu + residual + LN --------
// one wave per dst node; lane(h=lane>>4,m=lane&15): ea/ag channels 4m..4m+3 of
// head h; k/v channels 2*lane,2*lane+1 (bf16 interleaved in kvb)
__global__ __launch_bounds__(256) void k_attn(
    const float* __restrict__ nf, const ushort_t* __restrict__ kvb,
    const float* __restrict__ ea, const float* __restrict__ We,
    const int* __restrict__ offsets, const int2* __restrict__ pairs,
    const float* __restrict__ x, const float* __restrict__ wcomb,
    const float* __restrict__ gamma, const float* __restrict__ beta_ln,
    float* __restrict__ out) {
  __shared__ float lds_agg[4][292];
  int t = threadIdx.x, wv = t >> 6, lane = t & 63;
  int n = blockIdx.x * 4 + wv;
  int h = lane >> 4, m = lane & 15;
  int c0 = lane * 2, c1 = c0 + 1;
  const float scale = 0.17677669529663687f;   // 1/sqrt(32)

  const float* nrow = nf + (size_t)n * 512;
  float2 qv = *(const float2*)&nrow[c0];
  float q0 = qv.x * scale, q1 = qv.y * scale;
  float4 g4 = *(const float4*)&nrow[256 + h * 64 + 4 * m];
  g4.x *= scale; g4.y *= scale; g4.z *= scale; g4.w *= scale;

  int js = offsets[n], je = offsets[n + 1];
  float l = 0.f, acc0 = 0.f, acc1 = 0.f;
  float4 ag = make_float4(0.f, 0.f, 0.f, 0.f);

  for (int base = js; base < je; base += 64) {
    int nj = je - base; if (nj > 64) nj = 64;
    int2 pr = (lane < nj) ? pairs[base + lane] : make_int2(0, 0);
    int j = 0;
    for (; j + 4 <= nj; j += 4) {
      float4 ev[4]; uint2 kv[4];
#pragma unroll
      for (int u = 0; u < 4; ++u) {
        int eid = __builtin_amdgcn_readlane(pr.x, j + u);
        int s   = __builtin_amdgcn_readlane(pr.y, j + u);
        ev[u] = *(const float4*)&ea[(size_t)eid * 64 + 4 * m];
        kv[u] = *(const uint2*)&kvb[(size_t)s * 256 + 4 * lane];
      }
#pragma unroll
      for (int u = 0; u < 4; ++u) {
        float k0 = bflo(kv[u].x), k1 = bfhi(kv[u].x);
        float v0 = bflo(kv[u].y), v1 = bfhi(kv[u].y);
        float p = q0 * k0 + q1 * k1
                + g4.x * ev[u].x + g4.y * ev[u].y + g4.z * ev[u].z + g4.w * ev[u].w;
        p += __shfl_xor(p, 1); p += __shfl_xor(p, 2);
        p += __shfl_xor(p, 4); p += __shfl_xor(p, 8);
        float a = __expf(p);
        l += a;
        acc0 += a * v0; acc1 += a * v1;
        ag.x += a * ev[u].x; ag.y += a * ev[u].y;
        ag.z += a * ev[u].z; ag.w += a * ev[u].w;
      }
    }
    for (; j < nj; ++j) {
      int eid = __builtin_amdgcn_readlane(pr.x, j);
      int s   = __builtin_amdgcn_readlane(pr.y, j);
      float4 evs = *(const float4*)&ea[(size_t)eid * 64 + 4 * m];
      uint2 kvs = *(const uint2*)&kvb[(size_t)s * 256 + 4 * lane];
      float k0 = bflo(kvs.x), k1 = bfhi(kvs.x);
      float v0 = bflo(kvs.y), v1 = bfhi(kvs.y);
      float p = q0 * k0 + q1 * k1
              + g4.x * evs.x + g4.y * evs.y + g4.z * evs.z + g4.w * evs.w;
      p += __shfl_xor(p, 1); p += __shfl_xor(p, 2);
      p += __shfl_xor(p, 4); p += __shfl_xor(p, 8);
      float a = __expf(p);
      l += a;
      acc0 += a * v0; acc1 += a * v1;
      ag.x += a * evs.x; ag.y += a * evs.y; ag.z += a * evs.z; ag.w += a * evs.w;
    }
  }

  *(float4*)&lds_agg[wv][h * 72 + 4 * m] = ag;
  __syncthreads();
  float oe0 = 0.f, oe1 = 0.f;
  const float* ap = &lds_agg[wv][h * 72];
#pragma unroll 4
  for (int f = 0; f < 64; ++f) {
    float a = ap[f];
    float2 w2 = *(const float2*)&We[f * 128 + c0];
    oe0 += a * w2.x; oe1 += a * w2.y;
  }
  float inv = (l > 0.f) ? (1.0f / l) : 1.0f;
  float o0 = (acc0 + oe0) * inv;
  float o1 = (acc1 + oe1) * inv;

  float2 xrv = *(const float2*)&nrow[128 + c0];
  float bp = o0 * wcomb[c0] + o1 * wcomb[c1] + xrv.x * wcomb[128 + c0] + xrv.y * wcomb[128 + c1];
#pragma unroll
  for (int off = 32; off > 0; off >>= 1) bp += __shfl_xor(bp, off);
  float bgate = 1.0f / (1.0f + __expf(-bp));
  float r0 = bgate * xrv.x + (1.0f - bgate) * o0;
  float r1 = bgate * xrv.y + (1.0f - bgate) * o1;

  float2 xv = *(const float2*)&x[(size_t)n * 128 + c0];
  float ge0 = 0.5f * r0 * (1.0f + erff(r0 * 0.70710678118654752f)) + xv.x;
  float ge1 = 0.5f * r1 * (1.0f + erff(r1 * 0.70710678118654752f)) + xv.y;

  float s1 = ge0 + ge1;
  float s2 = ge0 * ge0 + ge1 * ge1;
#pragma unroll
  for (int off = 32; off > 0; off >>= 1) {
    s1 += __shfl_xor(s1, off);
    s2 += __shfl_xor(s2, off);
  }
  float mean = s1 * (1.0f / 128.0f);
  float var = s2 * (1.0f / 128.0f) - mean * mean;
  float rstd = rsqrtf(var + 1e-5f);
  float2 ov;
  ov.x = (ge0 - mean) * rstd * gamma[c0] + beta_ln[c0];
  ov.y = (ge1 - mean) * rstd * gamma[c1] + beta_ln[c1];
  *(float2*)&out[(size_t)n * 128 + c0] = ov;
}

// ---------------- launch ----------------
extern "C" void kernel_launch(void* const* d_in, const int* in_sizes, int n_in,
                              void* d_out, int out_size, void* d_ws, size_t ws_size,
                              hipStream_t stream) {
  const float* x   = (const float*)d_in[0];
  const int*   ei  = (const int*)d_in[1];
  const float* ea  = (const float*)d_in[2];
  const float* Wq  = (const float*)d_in[3];
  const float* bq  = (const float*)d_in[4];
  const float* Wk  = (const float*)d_in[5];
  const float* bk  = (const float*)d_in[6];
  const float* Wv  = (const float*)d_in[7];
  const float* bv  = (const float*)d_in[8];
  const float* We  = (const float*)d_in[9];
  const float* Wsk = (const float*)d_in[10];
  const float* bsk = (const float*)d_in[11];
  const float* Wb  = (const float*)d_in[12];
  const float* gamma = (const float*)d_in[13];
  const float* beta  = (const float*)d_in[14];
  float* out = (float*)d_out;

  char* cur = (char*)d_ws;
  auto alloc = [&](size_t bytes) {
    void* p = (void*)cur;
    cur += (bytes + 255) & ~(size_t)255;
    return p;
  };
  float*    nf      = (float*)alloc((size_t)NN * 512 * 4);
  ushort_t* kvb     = (ushort_t*)alloc((size_t)NN * 256 * 2);
  float*    wgq     = (float*)alloc(128 * 256 * 4);
  float*    bgq     = (float*)alloc(256 * 4);
  float*    wcomb   = (float*)alloc(256 * 4);
  float*    bcat    = (float*)alloc(768 * 4);
  ushort_t* Wbt     = (ushort_t*)alloc((size_t)768 * 128 * 2);
  int*      counts  = (int*)alloc((size_t)NN * 4);
  int*      offsets = (int*)alloc((size_t)(NN + 4) * 4);
  int2*     pairs   = (int2*)alloc((size_t)EE * 8);

  k_prepA<<<325, 256, 0, stream>>>(Wq, We, bq, Wb, wgq, bgq, wcomb, counts);
  k_prepB<<<384 + 3125, 256, 0, stream>>>(Wq, Wk, Wv, Wsk, wgq, bq, bk, bv, bsk, bgq,
                                          Wbt, bcat, ei, counts);
  k_mm<<<dim3(391, 6), 256, 0, stream>>>(x, Wbt, bcat, nf, kvb);
  k_scan<<<1, 1024, 0, stream>>>(counts, offsets);
  k_fill<<<3125, 256, 0, stream>>>(ei, counts, pairs);
  k_attn<<<12500, 256, 0, stream>>>(nf, kvb, ea, We, offsets, pairs, x, wcomb,
                                    gamma, beta, out);
}

// Round 4
// 373.540 us; speedup vs baseline: 2.5151x; 1.0530x over previous
//
#include <hip/hip_runtime.h>
#include <math.h>

#define NN 50000
#define EE 800000
// D=128, H=4, C=32, ED=64

typedef __bf16 bf16x8 __attribute__((ext_vector_type(8)));
typedef float f32x4 __attribute__((ext_vector_type(4)));
typedef unsigned short ushort_t;
typedef unsigned int uint_t;

__device__ inline ushort_t f2bf(float f) {
  uint_t u = __float_as_uint(f);
  uint_t r = (u + 0x7fffu + ((u >> 16) & 1u)) >> 16;
  return (ushort_t)r;
}
__device__ inline float bflo(uint_t u) { return __uint_as_float(u << 16); }
__device__ inline float bfhi(uint_t u) { return __uint_as_float(u & 0xffff0000u); }

__device__ inline void wave_sync() {
  asm volatile("s_waitcnt lgkmcnt(0)" ::: "memory");
  __builtin_amdgcn_wave_barrier();
}

// ---------------- prepA: wgq + small vectors + zero counts + zero pairs tail
__global__ __launch_bounds__(256) void k_prepA(const float* __restrict__ Wq,
                                               const float* __restrict__ We,
                                               const float* __restrict__ bq,
                                               const float* __restrict__ Wbeta,
                                               float* __restrict__ wgq,
                                               float* __restrict__ bgq,
                                               float* __restrict__ wcomb,
                                               int* __restrict__ counts,
                                               int* __restrict__ pairs_raw) {
  int b = blockIdx.x;
  int o = threadIdx.x;
  if (b < 128) {
    int kk = b, h = o >> 6, f = o & 63;
    float s = 0.f;
#pragma unroll
    for (int c = 0; c < 32; ++c)
      s += Wq[kk * 128 + h * 32 + c] * We[f * 128 + h * 32 + c];
    wgq[kk * 256 + o] = s;
  } else if (b == 128) {
    int h = o >> 6, f = o & 63;
    float s = 0.f;
#pragma unroll
    for (int c = 0; c < 32; ++c) s += bq[h * 32 + c] * We[f * 128 + h * 32 + c];
    bgq[o] = s;
    if (o < 128) {
      wcomb[o]       = Wbeta[o]       + Wbeta[256 + o];
      wcomb[128 + o] = Wbeta[128 + o] - Wbeta[256 + o];
    }
  } else if (b == 129) {
    if (o < 32) pairs_raw[2 * EE + o] = 0;   // zero pad tail of pairs
  } else {
    int i = (b - 130) * 256 + o;
    if (i < NN) counts[i] = 0;
  }
}

// ---------------- prepB: Wbt[768][128] bf16 + bcat + Web bf16 + hist --------
// Col map: [0,128)=q ; [128,256)=k ; [256,384)=v ; [384,512)=skip ; [512,768)=gq
__global__ __launch_bounds__(256) void k_prepB(
    const float* __restrict__ Wq, const float* __restrict__ Wk,
    const float* __restrict__ Wv, const float* __restrict__ Ws,
    const float* __restrict__ wgq,
    const float* __restrict__ bq, const float* __restrict__ bk,
    const float* __restrict__ bv, const float* __restrict__ bs,
    const float* __restrict__ bgq,
    ushort_t* __restrict__ Wbt, float* __restrict__ bcat,
    const float* __restrict__ We, ushort_t* __restrict__ Web,
    const int* __restrict__ ei, int* __restrict__ counts) {
  int b = blockIdx.x;
  if (b >= 416) {
    int i = (b - 416) * 256 + threadIdx.x;
    if (i < EE) atomicAdd(&counts[ei[EE + i]], 1);
    return;
  }
  if (b >= 384) {
    int i = (b - 384) * 256 + threadIdx.x;   // 0..8191
    Web[i] = f2bf(We[i]);
    return;
  }
  int i = b * 256 + threadIdx.x;   // 0..98303
  int c = i >> 7, k = i & 127;
  float w;
  if (c < 128)      w = Wq[k * 128 + c];
  else if (c < 256) w = Wk[k * 128 + (c - 128)];
  else if (c < 384) w = Wv[k * 128 + (c - 256)];
  else if (c < 512) w = Ws[k * 128 + (c - 384)];
  else              w = wgq[k * 256 + (c - 512)];
  Wbt[(size_t)c * 128 + k] = f2bf(w);
  if (i < 768) {
    float bb;
    if (i < 128)      bb = bq[i];
    else if (i < 256) bb = bk[i - 128];
    else if (i < 384) bb = bv[i - 256];
    else if (i < 512) bb = bs[i - 384];
    else              bb = bgq[i - 512];
    bcat[i] = bb;
  }
}

// ---------------- MFMA GEMM: [N,128] @ [128,768] + bias ---------------------
// cb: 0=q->nf[0:128), 128=k->kb bf16, 256=v->vb bf16, 384=xr->nf[128:256),
//     512,640=gq->nf[256:512)
__global__ __launch_bounds__(256) void k_mm(const float* __restrict__ x,
                                            const ushort_t* __restrict__ Wbt,
                                            const float* __restrict__ bcat,
                                            float* __restrict__ nf,
                                            ushort_t* __restrict__ kb,
                                            ushort_t* __restrict__ vb) {
  __shared__ ushort_t As[128 * 128];
  __shared__ ushort_t Bs[128 * 128];
  int t = threadIdx.x;
  int rb = blockIdx.x * 128;
  int cb = blockIdx.y * 128;

  for (int q = t; q < 2048; q += 256) {
    int r = q >> 4, j = q & 15;
    int row = rb + r;
    float4 f0 = make_float4(0.f, 0.f, 0.f, 0.f), f1 = f0;
    if (row < NN) {
      const float4* xp = (const float4*)&x[(size_t)row * 128 + j * 8];
      f0 = xp[0]; f1 = xp[1];
    }
    uint_t u0 = (uint_t)f2bf(f0.x) | ((uint_t)f2bf(f0.y) << 16);
    uint_t u1 = (uint_t)f2bf(f0.z) | ((uint_t)f2bf(f0.w) << 16);
    uint_t u2 = (uint_t)f2bf(f1.x) | ((uint_t)f2bf(f1.y) << 16);
    uint_t u3 = (uint_t)f2bf(f1.z) | ((uint_t)f2bf(f1.w) << 16);
    int e = r * 128 + ((j * 8) ^ ((r & 7) << 3));
    *(uint4*)&As[e] = make_uint4(u0, u1, u2, u3);
  }
  for (int q = t; q < 2048; q += 256) {
    int c = q >> 4, j = q & 15;
    uint4 w = *(const uint4*)&Wbt[(size_t)(cb + c) * 128 + j * 8];
    int e = c * 128 + ((j * 8) ^ ((c & 7) << 3));
    *(uint4*)&Bs[e] = w;
  }
  __syncthreads();

  int lane = t & 63;
  int wv = t >> 6;
  int wr = wv >> 1, wc = wv & 1;
  int l15 = lane & 15, l4 = lane >> 4;

  f32x4 acc[4][4];
#pragma unroll
  for (int i = 0; i < 4; ++i)
#pragma unroll
    for (int j = 0; j < 4; ++j) acc[i][j] = (f32x4){0.f, 0.f, 0.f, 0.f};

#pragma unroll
  for (int ks = 0; ks < 4; ++ks) {
    int kbv = ks * 32 + l4 * 8;
    bf16x8 af[4], bfr[4];
#pragma unroll
    for (int i = 0; i < 4; ++i) {
      int r = wr * 64 + i * 16 + l15;
      af[i] = *(const bf16x8*)&As[r * 128 + (kbv ^ ((r & 7) << 3))];
    }
#pragma unroll
    for (int j = 0; j < 4; ++j) {
      int c = wc * 64 + j * 16 + l15;
      bfr[j] = *(const bf16x8*)&Bs[c * 128 + (kbv ^ ((c & 7) << 3))];
    }
#pragma unroll
    for (int i = 0; i < 4; ++i)
#pragma unroll
      for (int j = 0; j < 4; ++j)
        acc[i][j] = __builtin_amdgcn_mfma_f32_16x16x32_bf16(af[i], bfr[j], acc[i][j], 0, 0, 0);
  }

  bool iskb = (cb == 128), isvb = (cb == 256);
#pragma unroll
  for (int j = 0; j < 4; ++j) {
    int colg = cb + wc * 64 + j * 16 + l15;
    float bv = bcat[colg];
#pragma unroll
    for (int i = 0; i < 4; ++i) {
#pragma unroll
      for (int reg = 0; reg < 4; ++reg) {
        int grow = rb + wr * 64 + i * 16 + l4 * 4 + reg;
        if (grow < NN) {
          float val = acc[i][j][reg] + bv;
          if (iskb)      kb[(size_t)grow * 128 + (colg - 128)] = f2bf(val);
          else if (isvb) vb[(size_t)grow * 128 + (colg - 256)] = f2bf(val);
          else {
            int nc = (colg < 128) ? colg : colg - 256;
            nf[(size_t)grow * 512 + nc] = val;
          }
        }
      }
    }
  }
}

// ---------------- single-block scan, int4-vectorized ------------------------
__global__ __launch_bounds__(1024) void k_scan(int* __restrict__ counts, int* __restrict__ offsets) {
  __shared__ int wsum[16];
  __shared__ int s_carry;
  int4* counts4 = (int4*)counts;
  int4* offsets4 = (int4*)offsets;
  int t = threadIdx.x, lane = t & 63, w = t >> 6;
  if (t == 0) s_carry = 0;
  __syncthreads();
  for (int base = 0; base < 12500; base += 1024) {
    int idx = base + t;
    int4 v = (idx < 12500) ? counts4[idx] : make_int4(0, 0, 0, 0);
    int e1 = v.x, e2 = e1 + v.y, e3 = e2 + v.z, tot = e3 + v.w;
    int s = tot;
#pragma unroll
    for (int off = 1; off < 64; off <<= 1) {
      int u = __shfl_up(s, off);
      if (lane >= off) s += u;
    }
    if (lane == 63) wsum[w] = s;
    __syncthreads();
    if (t == 0) {
      int ex = s_carry;
#pragma unroll
      for (int i = 0; i < 16; ++i) { int tv = wsum[i]; wsum[i] = ex; ex += tv; }
      s_carry = ex;
    }
    __syncthreads();
    int be = wsum[w] + s - tot;
    if (idx < 12500) {
      int4 o = make_int4(be, be + e1, be + e2, be + e3);
      offsets4[idx] = o;
      counts4[idx] = o;
    }
    __syncthreads();
  }
  if (t == 0) offsets[NN] = s_carry;
}

__global__ __launch_bounds__(256) void k_fill(const int* __restrict__ ei, int* __restrict__ cursors,
                                              int2* __restrict__ pairs) {
  int i = blockIdx.x * 256 + threadIdx.x;
  if (i < EE) {
    int d = ei[EE + i];
    int p = atomicAdd(&cursors[d], 1);
    pairs[p] = make_int2(i, ei[i]);
  }
}

// ---------------- fused attention + beta-gate + gelu + residual + LN --------
// 1 wave = 1 dst node. lane l: h=l>>4 (head), m=l&15 (edge slot).
// Chunks of 16 edges: lane (h,m) computes FULL score of edge m, head h.
__global__ __launch_bounds__(256) void k_attn(
    const float* __restrict__ nf, const ushort_t* __restrict__ kb,
    const ushort_t* __restrict__ vb, const float* __restrict__ ea,
    const ushort_t* __restrict__ Web,
    const int* __restrict__ offsets, const int2* __restrict__ pairs,
    const float* __restrict__ x, const float* __restrict__ wcomb,
    const float* __restrict__ gamma, const float* __restrict__ beta_ln,
    float* __restrict__ out) {
  __shared__ float sQ[4][128];
  __shared__ float sG[4][256];
  __shared__ float sEA[4][16][68];
  __shared__ float sA[4][64];
  __shared__ int   sS[4][16];

  int t = threadIdx.x, wv = t >> 6, l = t & 63;
  int n = blockIdx.x * 4 + wv;
  int h = l >> 4, m = l & 15;
  int c0 = 2 * l, c1 = c0 + 1;
  const float scale = 0.17677669529663687f;   // 1/sqrt(32)

  const float* nrow = nf + (size_t)n * 512;
  float2 q2 = *(const float2*)&nrow[c0];
  *(float2*)&sQ[wv][c0] = make_float2(q2.x * scale, q2.y * scale);
  float4 g4 = *(const float4*)&nrow[256 + 4 * l];
  *(float4*)&sG[wv][4 * l] = make_float4(g4.x * scale, g4.y * scale,
                                         g4.z * scale, g4.w * scale);
  if (l < 16) sS[wv][l] = 0;

  int js = offsets[n], je = offsets[n + 1];
  float acc0 = 0.f, acc1 = 0.f, lsum = 0.f;
  float4 ag = make_float4(0.f, 0.f, 0.f, 0.f);

  for (int base = js; base < je; base += 16) {
    int nj = je - base; if (nj > 16) nj = 16;
    wave_sync();   // prior chunk's readers done; prologue writes visible

    // ---- stage: each active lane loads its edge's ea quarter + k chunk ----
    uint4 k0, k1, k2, k3;
    if (m < nj) {
      int2 pr = pairs[base + m];
      const float4* earow = (const float4*)(ea + (size_t)pr.x * 64 + 16 * h);
      float4 e0 = earow[0], e1 = earow[1], e2 = earow[2], e3 = earow[3];
      const uint4* krow = (const uint4*)(kb + (size_t)pr.y * 128 + 32 * h);
      k0 = krow[0]; k1 = krow[1]; k2 = krow[2]; k3 = krow[3];
      if (h == 0) sS[wv][m] = pr.y;
      float* er = &sEA[wv][m][16 * h];
      *(float4*)&er[0]  = e0;
      *(float4*)&er[4]  = e1;
      *(float4*)&er[8]  = e2;
      *(float4*)&er[12] = e3;
    }
    wave_sync();

    // ---- score: z = q.k + g.ea (full, per (edge m, head h)) ----
    float z = 0.f;
    const float* gp = &sG[wv][64 * h];
    const float* ep = &sEA[wv][m][0];
#pragma unroll
    for (int u = 0; u < 16; ++u) {
      float4 g = *(const float4*)&gp[4 * u];
      float4 e = *(const float4*)&ep[4 * u];
      z += g.x * e.x + g.y * e.y + g.z * e.z + g.w * e.w;
    }
    const float* qp = &sQ[wv][32 * h];
    {
      uint4 ks_[4] = {k0, k1, k2, k3};
#pragma unroll
      for (int u = 0; u < 4; ++u) {
        float4 qa = *(const float4*)&qp[8 * u];
        float4 qb = *(const float4*)&qp[8 * u + 4];
        uint4 ku = ks_[u];
        z += qa.x * bflo(ku.x) + qa.y * bfhi(ku.x)
           + qa.z * bflo(ku.y) + qa.w * bfhi(ku.y);
        z += qb.x * bflo(ku.z) + qb.y * bfhi(ku.z)
           + qb.z * bflo(ku.w) + qb.w * bfhi(ku.w);
      }
    }
    float a = (m < nj) ? __expf(z) : 0.0f;
    lsum += a;
    sA[wv][l] = a;
    wave_sync();

    // ---- phase B: weighted V + weighted ea accumulation ----
    int4 s0 = *(const int4*)&sS[wv][0];
    int4 s1 = *(const int4*)&sS[wv][4];
    f32x4 a0 = *(const f32x4*)&sA[wv][16 * h];
    f32x4 a1 = *(const f32x4*)&sA[wv][16 * h + 4];
    {
      uint_t vv[8];
      int sidx[8] = {s0.x, s0.y, s0.z, s0.w, s1.x, s1.y, s1.z, s1.w};
#pragma unroll
      for (int e = 0; e < 8; ++e)
        vv[e] = *(const uint_t*)(vb + (size_t)sidx[e] * 128 + c0);
#pragma unroll
      for (int e = 0; e < 8; ++e) {
        float ae = (e < 4) ? a0[e] : a1[e - 4];
        acc0 += ae * bflo(vv[e]); acc1 += ae * bfhi(vv[e]);
        float4 er = *(const float4*)&sEA[wv][e][4 * m];
        ag.x += ae * er.x; ag.y += ae * er.y;
        ag.z += ae * er.z; ag.w += ae * er.w;
      }
    }
    if (nj > 8) {
      int4 s2 = *(const int4*)&sS[wv][8];
      int4 s3 = *(const int4*)&sS[wv][12];
      f32x4 a2 = *(const f32x4*)&sA[wv][16 * h + 8];
      f32x4 a3 = *(const f32x4*)&sA[wv][16 * h + 12];
      uint_t vv[8];
      int sidx[8] = {s2.x, s2.y, s2.z, s2.w, s3.x, s3.y, s3.z, s3.w};
#pragma unroll
      for (int e = 0; e < 8; ++e)
        vv[e] = *(const uint_t*)(vb + (size_t)sidx[e] * 128 + c0);
#pragma unroll
      for (int e = 0; e < 8; ++e) {
        float ae = (e < 4) ? a2[e] : a3[e - 4];
        acc0 += ae * bflo(vv[e]); acc1 += ae * bfhi(vv[e]);
        float4 er = *(const float4*)&sEA[wv][8 + e][4 * m];
        ag.x += ae * er.x; ag.y += ae * er.y;
        ag.z += ae * er.z; ag.w += ae * er.w;
      }
    }
  }

  // ---- epilogue ----
  lsum += __shfl_xor(lsum, 1); lsum += __shfl_xor(lsum, 2);
  lsum += __shfl_xor(lsum, 4); lsum += __shfl_xor(lsum, 8);

  wave_sync();
  *(float4*)&sEA[wv][h][4 * m] = ag;    // reuse rows 0..3 as ag[h][64]
  wave_sync();

  float oe0 = 0.f, oe1 = 0.f;
  const float* agp = &sEA[wv][h][0];
  const uint_t* webp = (const uint_t*)Web + l;
#pragma unroll 8
  for (int f = 0; f < 64; ++f) {
    float av = agp[f];
    uint_t w = webp[f * 64];
    oe0 += av * bflo(w); oe1 += av * bfhi(w);
  }

  float inv = (lsum > 0.f) ? (1.0f / lsum) : 1.0f;
  float o0 = (acc0 + oe0) * inv;
  float o1 = (acc1 + oe1) * inv;

  float2 xrv = *(const float2*)&nrow[128 + c0];
  float bp = o0 * wcomb[c0] + o1 * wcomb[c1] + xrv.x * wcomb[128 + c0] + xrv.y * wcomb[128 + c1];
#pragma unroll
  for (int off = 32; off > 0; off >>= 1) bp += __shfl_xor(bp, off);
  float bgate = 1.0f / (1.0f + __expf(-bp));
  float r0 = bgate * xrv.x + (1.0f - bgate) * o0;
  float r1 = bgate * xrv.y + (1.0f - bgate) * o1;

  float2 xv = *(const float2*)&x[(size_t)n * 128 + c0];
  float ge0 = 0.5f * r0 * (1.0f + erff(r0 * 0.70710678118654752f)) + xv.x;
  float ge1 = 0.5f * r1 * (1.0f + erff(r1 * 0.70710678118654752f)) + xv.y;

  float s1 = ge0 + ge1;
  float s2 = ge0 * ge0 + ge1 * ge1;
#pragma unroll
  for (int off = 32; off > 0; off >>= 1) {
    s1 += __shfl_xor(s1, off);
    s2 += __shfl_xor(s2, off);
  }
  float mean = s1 * (1.0f / 128.0f);
  float var = s2 * (1.0f / 128.0f) - mean * mean;
  float rstd = rsqrtf(var + 1e-5f);
  float2 ov;
  ov.x = (ge0 - mean) * rstd * gamma[c0] + beta_ln[c0];
  ov.y = (ge1 - mean) * rstd * gamma[c1] + beta_ln[c1];
  *(float2*)&out[(size_t)n * 128 + c0] = ov;
}

// ---------------- launch ----------------
extern "C" void kernel_launch(void* const* d_in, const int* in_sizes, int n_in,
                              void* d_out, int out_size, void* d_ws, size_t ws_size,
                              hipStream_t stream) {
  const float* x   = (const float*)d_in[0];
  const int*   ei  = (const int*)d_in[1];
  const float* ea  = (const float*)d_in[2];
  const float* Wq  = (const float*)d_in[3];
  const float* bq  = (const float*)d_in[4];
  const float* Wk  = (const float*)d_in[5];
  const float* bk  = (const float*)d_in[6];
  const float* Wv  = (const float*)d_in[7];
  const float* bv  = (const float*)d_in[8];
  const float* We  = (const float*)d_in[9];
  const float* Wsk = (const float*)d_in[10];
  const float* bsk = (const float*)d_in[11];
  const float* Wb  = (const float*)d_in[12];
  const float* gamma = (const float*)d_in[13];
  const float* beta  = (const float*)d_in[14];
  float* out = (float*)d_out;

  char* cur = (char*)d_ws;
  auto alloc = [&](size_t bytes) {
    void* p = (void*)cur;
    cur += (bytes + 255) & ~(size_t)255;
    return p;
  };
  float*    nf      = (float*)alloc((size_t)NN * 512 * 4);
  ushort_t* kbuf    = (ushort_t*)alloc((size_t)NN * 128 * 2);
  ushort_t* vbuf    = (ushort_t*)alloc((size_t)NN * 128 * 2);
  float*    wgq     = (float*)alloc(128 * 256 * 4);
  float*    bgq     = (float*)alloc(256 * 4);
  float*    wcomb   = (float*)alloc(256 * 4);
  float*    bcat    = (float*)alloc(768 * 4);
  ushort_t* Wbt     = (ushort_t*)alloc((size_t)768 * 128 * 2);
  ushort_t* Web     = (ushort_t*)alloc((size_t)64 * 128 * 2);
  int*      counts  = (int*)alloc((size_t)NN * 4);
  int*      offsets = (int*)alloc((size_t)(NN + 4) * 4);
  int2*     pairs   = (int2*)alloc((size_t)(EE + 16) * 8);

  k_prepA<<<326, 256, 0, stream>>>(Wq, We, bq, Wb, wgq, bgq, wcomb, counts, (int*)pairs);
  k_prepB<<<416 + 3125, 256, 0, stream>>>(Wq, Wk, Wv, Wsk, wgq, bq, bk, bv, bsk, bgq,
                                          Wbt, bcat, We, Web, ei, counts);
  k_mm<<<dim3(391, 6), 256, 0, stream>>>(x, Wbt, bcat, nf, kbuf, vbuf);
  k_scan<<<1, 1024, 0, stream>>>(counts, offsets);
  k_fill<<<3125, 256, 0, stream>>>(ei, counts, pairs);
  k_attn<<<12500, 256, 0, stream>>>(nf, kbuf, vbuf, ea, Web, offsets, pairs, x,
                                    wcomb, gamma, beta, out);
}

// Round 5
// 356.465 us; speedup vs baseline: 2.6356x; 1.0479x over previous
//
#include <hip/hip_runtime.h>
#include <math.h>

#define NN 50000
#define EE 800000
// D=128, H=4, C=32, ED=64

typedef __bf16 bf16x8 __attribute__((ext_vector_type(8)));
typedef float f32x4 __attribute__((ext_vector_type(4)));
typedef unsigned short ushort_t;
typedef unsigned int uint_t;

__device__ inline ushort_t f2bf(float f) {
  uint_t u = __float_as_uint(f);
  uint_t r = (u + 0x7fffu + ((u >> 16) & 1u)) >> 16;
  return (ushort_t)r;
}
__device__ inline float bflo(uint_t u) { return __uint_as_float(u << 16); }
__device__ inline float bfhi(uint_t u) { return __uint_as_float(u & 0xffff0000u); }

__device__ inline void wave_sync() {
  asm volatile("s_waitcnt lgkmcnt(0)" ::: "memory");
  __builtin_amdgcn_wave_barrier();
}

// ---------------- prepA: wgq + small vectors + zero counts ------------------
__global__ __launch_bounds__(256) void k_prepA(const float* __restrict__ Wq,
                                               const float* __restrict__ We,
                                               const float* __restrict__ bq,
                                               const float* __restrict__ Wbeta,
                                               float* __restrict__ wgq,
                                               float* __restrict__ bgq,
                                               float* __restrict__ wcomb,
                                               int* __restrict__ counts) {
  int b = blockIdx.x;
  int o = threadIdx.x;
  if (b < 128) {
    int kk = b, h = o >> 6, f = o & 63;
    float s = 0.f;
#pragma unroll
    for (int c = 0; c < 32; ++c)
      s += Wq[kk * 128 + h * 32 + c] * We[f * 128 + h * 32 + c];
    wgq[kk * 256 + o] = s;
  } else if (b == 128) {
    int h = o >> 6, f = o & 63;
    float s = 0.f;
#pragma unroll
    for (int c = 0; c < 32; ++c) s += bq[h * 32 + c] * We[f * 128 + h * 32 + c];
    bgq[o] = s;
    if (o < 128) {
      wcomb[o]       = Wbeta[o]       + Wbeta[256 + o];
      wcomb[128 + o] = Wbeta[128 + o] - Wbeta[256 + o];
    }
  } else {
    int i = (b - 129) * 256 + o;
    if (i < NN) counts[i] = 0;
  }
}

// ---------------- prepB: Wbt[768][128] bf16 + bcat + Web bf16 + hist --------
// Col map: [0,128)=q ; [128,256)=k ; [256,384)=v ; [384,512)=skip ; [512,768)=gq
__global__ __launch_bounds__(256) void k_prepB(
    const float* __restrict__ Wq, const float* __restrict__ Wk,
    const float* __restrict__ Wv, const float* __restrict__ Ws,
    const float* __restrict__ wgq,
    const float* __restrict__ bq, const float* __restrict__ bk,
    const float* __restrict__ bv, const float* __restrict__ bs,
    const float* __restrict__ bgq,
    ushort_t* __restrict__ Wbt, float* __restrict__ bcat,
    const float* __restrict__ We, ushort_t* __restrict__ Web,
    const int* __restrict__ ei, int* __restrict__ counts) {
  int b = blockIdx.x;
  if (b >= 416) {
    int i = (b - 416) * 256 + threadIdx.x;
    if (i < EE) atomicAdd(&counts[ei[EE + i]], 1);
    return;
  }
  if (b >= 384) {
    int i = (b - 384) * 256 + threadIdx.x;   // 0..8191
    Web[i] = f2bf(We[i]);
    return;
  }
  int i = b * 256 + threadIdx.x;   // 0..98303
  int c = i >> 7, k = i & 127;
  float w;
  if (c < 128)      w = Wq[k * 128 + c];
  else if (c < 256) w = Wk[k * 128 + (c - 128)];
  else if (c < 384) w = Wv[k * 128 + (c - 256)];
  else if (c < 512) w = Ws[k * 128 + (c - 384)];
  else              w = wgq[k * 256 + (c - 512)];
  Wbt[(size_t)c * 128 + k] = f2bf(w);
  if (i < 768) {
    float bb;
    if (i < 128)      bb = bq[i];
    else if (i < 256) bb = bk[i - 128];
    else if (i < 384) bb = bv[i - 256];
    else if (i < 512) bb = bs[i - 384];
    else              bb = bgq[i - 512];
    bcat[i] = bb;
  }
}

// ---------------- MFMA GEMM: [N,128] @ [128,768] + bias ---------------------
// cb: 0=q->nqx[0:128) f32, 128=k->kb bf16, 256=v->vb bf16,
//     384=xr->nqx[128:256) f32, 512/640=gq->gqb bf16
__global__ __launch_bounds__(256) void k_mm(const float* __restrict__ x,
                                            const ushort_t* __restrict__ Wbt,
                                            const float* __restrict__ bcat,
                                            float* __restrict__ nqx,
                                            ushort_t* __restrict__ kb,
                                            ushort_t* __restrict__ vb,
                                            ushort_t* __restrict__ gqb) {
  __shared__ ushort_t As[128 * 128];
  __shared__ ushort_t Bs[128 * 128];
  int t = threadIdx.x;
  int rb = blockIdx.x * 128;
  int cb = blockIdx.y * 128;

  for (int q = t; q < 2048; q += 256) {
    int r = q >> 4, j = q & 15;
    int row = rb + r;
    float4 f0 = make_float4(0.f, 0.f, 0.f, 0.f), f1 = f0;
    if (row < NN) {
      const float4* xp = (const float4*)&x[(size_t)row * 128 + j * 8];
      f0 = xp[0]; f1 = xp[1];
    }
    uint_t u0 = (uint_t)f2bf(f0.x) | ((uint_t)f2bf(f0.y) << 16);
    uint_t u1 = (uint_t)f2bf(f0.z) | ((uint_t)f2bf(f0.w) << 16);
    uint_t u2 = (uint_t)f2bf(f1.x) | ((uint_t)f2bf(f1.y) << 16);
    uint_t u3 = (uint_t)f2bf(f1.z) | ((uint_t)f2bf(f1.w) << 16);
    int e = r * 128 + ((j * 8) ^ ((r & 7) << 3));
    *(uint4*)&As[e] = make_uint4(u0, u1, u2, u3);
  }
  for (int q = t; q < 2048; q += 256) {
    int c = q >> 4, j = q & 15;
    uint4 w = *(const uint4*)&Wbt[(size_t)(cb + c) * 128 + j * 8];
    int e = c * 128 + ((j * 8) ^ ((c & 7) << 3));
    *(uint4*)&Bs[e] = w;
  }
  __syncthreads();

  int lane = t & 63;
  int wv = t >> 6;
  int wr = wv >> 1, wc = wv & 1;
  int l15 = lane & 15, l4 = lane >> 4;

  f32x4 acc[4][4];
#pragma unroll
  for (int i = 0; i < 4; ++i)
#pragma unroll
    for (int j = 0; j < 4; ++j) acc[i][j] = (f32x4){0.f, 0.f, 0.f, 0.f};

#pragma unroll
  for (int ks = 0; ks < 4; ++ks) {
    int kbv = ks * 32 + l4 * 8;
    bf16x8 af[4], bfr[4];
#pragma unroll
    for (int i = 0; i < 4; ++i) {
      int r = wr * 64 + i * 16 + l15;
      af[i] = *(const bf16x8*)&As[r * 128 + (kbv ^ ((r & 7) << 3))];
    }
#pragma unroll
    for (int j = 0; j < 4; ++j) {
      int c = wc * 64 + j * 16 + l15;
      bfr[j] = *(const bf16x8*)&Bs[c * 128 + (kbv ^ ((c & 7) << 3))];
    }
#pragma unroll
    for (int i = 0; i < 4; ++i)
#pragma unroll
      for (int j = 0; j < 4; ++j)
        acc[i][j] = __builtin_amdgcn_mfma_f32_16x16x32_bf16(af[i], bfr[j], acc[i][j], 0, 0, 0);
  }

#pragma unroll
  for (int j = 0; j < 4; ++j) {
    int colg = cb + wc * 64 + j * 16 + l15;
    float bv = bcat[colg];
#pragma unroll
    for (int i = 0; i < 4; ++i) {
#pragma unroll
      for (int reg = 0; reg < 4; ++reg) {
        int grow = rb + wr * 64 + i * 16 + l4 * 4 + reg;
        if (grow < NN) {
          float val = acc[i][j][reg] + bv;
          if (cb == 0)        nqx[(size_t)grow * 256 + colg] = val;
          else if (cb == 128) kb[(size_t)grow * 128 + (colg - 128)] = f2bf(val);
          else if (cb == 256) vb[(size_t)grow * 128 + (colg - 256)] = f2bf(val);
          else if (cb == 384) nqx[(size_t)grow * 256 + (colg - 256)] = val;
          else                gqb[(size_t)grow * 256 + (colg - 512)] = f2bf(val);
        }
      }
    }
  }
}

// ---------------- single-block scan, int4-vectorized ------------------------
__global__ __launch_bounds__(1024) void k_scan(int* __restrict__ counts, int* __restrict__ offsets) {
  __shared__ int wsum[16];
  __shared__ int s_carry;
  int4* counts4 = (int4*)counts;
  int4* offsets4 = (int4*)offsets;
  int t = threadIdx.x, lane = t & 63, w = t >> 6;
  if (t == 0) s_carry = 0;
  __syncthreads();
  for (int base = 0; base < 12500; base += 1024) {
    int idx = base + t;
    int4 v = (idx < 12500) ? counts4[idx] : make_int4(0, 0, 0, 0);
    int e1 = v.x, e2 = e1 + v.y, e3 = e2 + v.z, tot = e3 + v.w;
    int s = tot;
#pragma unroll
    for (int off = 1; off < 64; off <<= 1) {
      int u = __shfl_up(s, off);
      if (lane >= off) s += u;
    }
    if (lane == 63) wsum[w] = s;
    __syncthreads();
    if (t == 0) {
      int ex = s_carry;
#pragma unroll
      for (int i = 0; i < 16; ++i) { int tv = wsum[i]; wsum[i] = ex; ex += tv; }
      s_carry = ex;
    }
    __syncthreads();
    int be = wsum[w] + s - tot;
    if (idx < 12500) {
      int4 o = make_int4(be, be + e1, be + e2, be + e3);
      offsets4[idx] = o;
      counts4[idx] = o;
    }
    __syncthreads();
  }
  if (t == 0) offsets[NN] = s_carry;
}

// ---------------- fill: CSR srcs + permute ea into CSR order as bf16 --------
// block = 256 threads = 64 edges; 4 threads per edge (qt = quarter of 64 ch)
__global__ __launch_bounds__(256) void k_fill(const int* __restrict__ ei,
                                              int* __restrict__ cursors,
                                              const float* __restrict__ ea,
                                              int* __restrict__ srcs,
                                              ushort_t* __restrict__ eaperm) {
  int t = threadIdx.x;
  int lane = t & 63;
  int e = blockIdx.x * 64 + (t >> 2);       // 12500*64 == EE exactly
  int qt = t & 3;
  int d = ei[EE + e];
  int p = 0;
  if (qt == 0) p = atomicAdd(&cursors[d], 1);
  p = __shfl(p, lane & ~3);
  const float4* src4 = (const float4*)(ea + (size_t)e * 64 + qt * 16);
  float4 f0 = src4[0], f1 = src4[1], f2 = src4[2], f3 = src4[3];
  uint4 o0, o1;
  o0.x = (uint_t)f2bf(f0.x) | ((uint_t)f2bf(f0.y) << 16);
  o0.y = (uint_t)f2bf(f0.z) | ((uint_t)f2bf(f0.w) << 16);
  o0.z = (uint_t)f2bf(f1.x) | ((uint_t)f2bf(f1.y) << 16);
  o0.w = (uint_t)f2bf(f1.z) | ((uint_t)f2bf(f1.w) << 16);
  o1.x = (uint_t)f2bf(f2.x) | ((uint_t)f2bf(f2.y) << 16);
  o1.y = (uint_t)f2bf(f2.z) | ((uint_t)f2bf(f2.w) << 16);
  o1.z = (uint_t)f2bf(f3.x) | ((uint_t)f2bf(f3.y) << 16);
  o1.w = (uint_t)f2bf(f3.z) | ((uint_t)f2bf(f3.w) << 16);
  ushort_t* dst = eaperm + (size_t)p * 64 + qt * 16;
  *(uint4*)dst = o0;
  *((uint4*)dst + 1) = o1;
  if (qt == 0) srcs[p] = ei[e];
}

// ---------------- fused attention + beta-gate + gelu + residual + LN --------
// 1 wave = 1 dst node. lane l: h=l>>4 (head), m=l&15 (edge slot).
__global__ __launch_bounds__(256) void k_attn(
    const float* __restrict__ nqx, const ushort_t* __restrict__ gqb,
    const ushort_t* __restrict__ kb, const ushort_t* __restrict__ vb,
    const ushort_t* __restrict__ eaperm, const ushort_t* __restrict__ Web,
    const int* __restrict__ offsets, const int* __restrict__ srcs,
    const float* __restrict__ x, const float* __restrict__ wcomb,
    const float* __restrict__ gamma, const float* __restrict__ beta_ln,
    float* __restrict__ out) {
  __shared__ float sQ[4][128];
  __shared__ float sG[4][256];
  __shared__ ushort_t sEA[4][16][72];   // 64 bf16 + pad, rows 144B (16B-aligned)
  __shared__ float sA[4][64];
  __shared__ int   sS[4][16];

  int t = threadIdx.x, wv = t >> 6, l = t & 63;
  int n = blockIdx.x * 4 + wv;
  int h = l >> 4, m = l & 15;
  int c0 = 2 * l, c1 = c0 + 1;
  const float scale = 0.17677669529663687f;   // 1/sqrt(32)

  const float* nrow = nqx + (size_t)n * 256;
  float2 q2 = *(const float2*)&nrow[c0];
  *(float2*)&sQ[wv][c0] = make_float2(q2.x * scale, q2.y * scale);
  uint2 gw = *(const uint2*)(gqb + (size_t)n * 256 + 4 * l);
  *(float4*)&sG[wv][4 * l] = make_float4(bflo(gw.x) * scale, bfhi(gw.x) * scale,
                                         bflo(gw.y) * scale, bfhi(gw.y) * scale);
  if (l < 16) sS[wv][l] = 0;

  int js = offsets[n], je = offsets[n + 1];
  float acc0 = 0.f, acc1 = 0.f, lsum = 0.f;
  float4 ag = make_float4(0.f, 0.f, 0.f, 0.f);

  for (int base = js; base < je; base += 16) {
    int nj = je - base; if (nj > 16) nj = 16;
    wave_sync();   // prior chunk's readers done; prologue writes visible

    uint4 k0 = {0,0,0,0}, k1 = {0,0,0,0}, k2 = {0,0,0,0}, k3 = {0,0,0,0};
    if (m < nj) {
      int s = srcs[base + m];
      const uint4* erow = (const uint4*)(eaperm + (size_t)(base + m) * 64 + 16 * h);
      uint4 e0 = erow[0], e1 = erow[1];
      const uint4* krow = (const uint4*)(kb + (size_t)s * 128 + 32 * h);
      k0 = krow[0]; k1 = krow[1]; k2 = krow[2]; k3 = krow[3];
      if (h == 0) sS[wv][m] = s;
      *(uint4*)&sEA[wv][m][16 * h] = e0;
      *(uint4*)&sEA[wv][m][16 * h + 8] = e1;
    }
    wave_sync();

    // ---- score z = q.k + g.ea for (edge m, head h) ----
    float z = 0.f;
    {
      const float* gp = &sG[wv][64 * h];
      const ushort_t* ep = &sEA[wv][m][0];
#pragma unroll
      for (int u = 0; u < 8; ++u) {
        uint4 w = *(const uint4*)&ep[8 * u];
        float4 ga = *(const float4*)&gp[8 * u];
        float4 gb = *(const float4*)&gp[8 * u + 4];
        z += ga.x * bflo(w.x) + ga.y * bfhi(w.x) + ga.z * bflo(w.y) + ga.w * bfhi(w.y)
           + gb.x * bflo(w.z) + gb.y * bfhi(w.z) + gb.z * bflo(w.w) + gb.w * bfhi(w.w);
      }
    }
    {
      const float* qp = &sQ[wv][32 * h];
      uint4 ks_[4] = {k0, k1, k2, k3};
#pragma unroll
      for (int u = 0; u < 4; ++u) {
        float4 qa = *(const float4*)&qp[8 * u];
        float4 qb = *(const float4*)&qp[8 * u + 4];
        uint4 ku = ks_[u];
        z += qa.x * bflo(ku.x) + qa.y * bfhi(ku.x)
           + qa.z * bflo(ku.y) + qa.w * bfhi(ku.y);
        z += qb.x * bflo(ku.z) + qb.y * bfhi(ku.z)
           + qb.z * bflo(ku.w) + qb.w * bfhi(ku.w);
      }
    }
    float a = (m < nj) ? __expf(z) : 0.0f;
    lsum += a;
    sA[wv][l] = a;
    wave_sync();

    // ---- phase B: weighted V + weighted ea accumulation ----
    int4 s0 = *(const int4*)&sS[wv][0];
    int4 s1 = *(const int4*)&sS[wv][4];
    f32x4 a0 = *(const f32x4*)&sA[wv][16 * h];
    f32x4 a1 = *(const f32x4*)&sA[wv][16 * h + 4];
    {
      uint_t vv[8];
      int sidx[8] = {s0.x, s0.y, s0.z, s0.w, s1.x, s1.y, s1.z, s1.w};
#pragma unroll
      for (int e = 0; e < 8; ++e)
        vv[e] = *(const uint_t*)(vb + (size_t)sidx[e] * 128 + c0);
#pragma unroll
      for (int e = 0; e < 8; ++e) {
        float ae = (e < 4) ? a0[e] : a1[e - 4];
        acc0 += ae * bflo(vv[e]); acc1 += ae * bfhi(vv[e]);
        uint2 er = *(const uint2*)&sEA[wv][e][4 * m];
        ag.x += ae * bflo(er.x); ag.y += ae * bfhi(er.x);
        ag.z += ae * bflo(er.y); ag.w += ae * bfhi(er.y);
      }
    }
    if (nj > 8) {
      int4 s2 = *(const int4*)&sS[wv][8];
      int4 s3 = *(const int4*)&sS[wv][12];
      f32x4 a2 = *(const f32x4*)&sA[wv][16 * h + 8];
      f32x4 a3 = *(const f32x4*)&sA[wv][16 * h + 12];
      uint_t vv[8];
      int sidx[8] = {s2.x, s2.y, s2.z, s2.w, s3.x, s3.y, s3.z, s3.w};
#pragma unroll
      for (int e = 0; e < 8; ++e)
        vv[e] = *(const uint_t*)(vb + (size_t)sidx[e] * 128 + c0);
#pragma unroll
      for (int e = 0; e < 8; ++e) {
        float ae = (e < 4) ? a2[e] : a3[e - 4];
        acc0 += ae * bflo(vv[e]); acc1 += ae * bfhi(vv[e]);
        uint2 er = *(const uint2*)&sEA[wv][8 + e][4 * m];
        ag.x += ae * bflo(er.x); ag.y += ae * bfhi(er.x);
        ag.z += ae * bflo(er.y); ag.w += ae * bfhi(er.y);
      }
    }
  }

  // ---- epilogue ----
  lsum += __shfl_xor(lsum, 1); lsum += __shfl_xor(lsum, 2);
  lsum += __shfl_xor(lsum, 4); lsum += __shfl_xor(lsum, 8);

  wave_sync();
  *(float4*)&sG[wv][64 * h + 4 * m] = ag;   // reuse sG as Agg[h][64]
  wave_sync();

  float oe0 = 0.f, oe1 = 0.f;
  const float* agp = &sG[wv][64 * h];
  const uint_t* webp = (const uint_t*)Web + l;
#pragma unroll 8
  for (int f = 0; f < 64; ++f) {
    float av = agp[f];
    uint_t w = webp[f * 64];
    oe0 += av * bflo(w); oe1 += av * bfhi(w);
  }

  float inv = (lsum > 0.f) ? (1.0f / lsum) : 1.0f;
  float o0 = (acc0 + oe0) * inv;
  float o1 = (acc1 + oe1) * inv;

  float2 xrv = *(const float2*)&nrow[128 + c0];
  float bp = o0 * wcomb[c0] + o1 * wcomb[c1] + xrv.x * wcomb[128 + c0] + xrv.y * wcomb[128 + c1];
#pragma unroll
  for (int off = 32; off > 0; off >>= 1) bp += __shfl_xor(bp, off);
  float bgate = 1.0f / (1.0f + __expf(-bp));
  float r0 = bgate * xrv.x + (1.0f - bgate) * o0;
  float r1 = bgate * xrv.y + (1.0f - bgate) * o1;

  float2 xv = *(const float2*)&x[(size_t)n * 128 + c0];
  float ge0 = 0.5f * r0 * (1.0f + erff(r0 * 0.70710678118654752f)) + xv.x;
  float ge1 = 0.5f * r1 * (1.0f + erff(r1 * 0.70710678118654752f)) + xv.y;

  float s1 = ge0 + ge1;
  float s2 = ge0 * ge0 + ge1 * ge1;
#pragma unroll
  for (int off = 32; off > 0; off >>= 1) {
    s1 += __shfl_xor(s1, off);
    s2 += __shfl_xor(s2, off);
  }
  float mean = s1 * (1.0f / 128.0f);
  float var = s2 * (1.0f / 128.0f) - mean * mean;
  float rstd = rsqrtf(var + 1e-5f);
  float2 ov;
  ov.x = (ge0 - mean) * rstd * gamma[c0] + beta_ln[c0];
  ov.y = (ge1 - mean) * rstd * gamma[c1] + beta_ln[c1];
  *(float2*)&out[(size_t)n * 128 + c0] = ov;
}

// ---------------- launch ----------------
extern "C" void kernel_launch(void* const* d_in, const int* in_sizes, int n_in,
                              void* d_out, int out_size, void* d_ws, size_t ws_size,
                              hipStream_t stream) {
  const float* x   = (const float*)d_in[0];
  const int*   ei  = (const int*)d_in[1];
  const float* ea  = (const float*)d_in[2];
  const float* Wq  = (const float*)d_in[3];
  const float* bq  = (const float*)d_in[4];
  const float* Wk  = (const float*)d_in[5];
  const float* bk  = (const float*)d_in[6];
  const float* Wv  = (const float*)d_in[7];
  const float* bv  = (const float*)d_in[8];
  const float* We  = (const float*)d_in[9];
  const float* Wsk = (const float*)d_in[10];
  const float* bsk = (const float*)d_in[11];
  const float* Wb  = (const float*)d_in[12];
  const float* gamma = (const float*)d_in[13];
  const float* beta  = (const float*)d_in[14];
  float* out = (float*)d_out;

  char* cur = (char*)d_ws;
  auto alloc = [&](size_t bytes) {
    void* p = (void*)cur;
    cur += (bytes + 255) & ~(size_t)255;
    return p;
  };
  float*    nqx     = (float*)alloc((size_t)NN * 256 * 4);      // q | xr (f32)
  ushort_t* gqb     = (ushort_t*)alloc((size_t)NN * 256 * 2);   // gq bf16
  ushort_t* kbuf    = (ushort_t*)alloc((size_t)NN * 128 * 2);
  ushort_t* vbuf    = (ushort_t*)alloc((size_t)NN * 128 * 2);
  ushort_t* eaperm  = (ushort_t*)alloc((size_t)EE * 64 * 2);    // ea bf16, CSR order
  int*      srcs    = (int*)alloc((size_t)EE * 4);
  float*    wgq     = (float*)alloc(128 * 256 * 4);
  float*    bgq     = (float*)alloc(256 * 4);
  float*    wcomb   = (float*)alloc(256 * 4);
  float*    bcat    = (float*)alloc(768 * 4);
  ushort_t* Wbt     = (ushort_t*)alloc((size_t)768 * 128 * 2);
  ushort_t* Web     = (ushort_t*)alloc((size_t)64 * 128 * 2);
  int*      counts  = (int*)alloc((size_t)NN * 4);
  int*      offsets = (int*)alloc((size_t)(NN + 4) * 4);

  k_prepA<<<325, 256, 0, stream>>>(Wq, We, bq, Wb, wgq, bgq, wcomb, counts);
  k_prepB<<<416 + 3125, 256, 0, stream>>>(Wq, Wk, Wv, Wsk, wgq, bq, bk, bv, bsk, bgq,
                                          Wbt, bcat, We, Web, ei, counts);
  k_mm<<<dim3(391, 6), 256, 0, stream>>>(x, Wbt, bcat, nqx, kbuf, vbuf, gqb);
  k_scan<<<1, 1024, 0, stream>>>(counts, offsets);
  k_fill<<<12500, 256, 0, stream>>>(ei, counts, ea, srcs, eaperm);
  k_attn<<<12500, 256, 0, stream>>>(nqx, gqb, kbuf, vbuf, eaperm, Web, offsets,
                                    srcs, x, wcomb, gamma, beta, out);
}

// Round 8
// 333.466 us; speedup vs baseline: 2.8174x; 1.0690x over previous
//
#include <hip/hip_runtime.h>
#include <math.h>

#define NN 50000
#define EE 800000
// D=128, H=4, C=32, ED=64

typedef __bf16 bf16x8 __attribute__((ext_vector_type(8)));
typedef float f32x4 __attribute__((ext_vector_type(4)));
typedef float f32x2 __attribute__((ext_vector_type(2)));
typedef unsigned short ushort_t;
typedef unsigned int uint_t;

__device__ inline ushort_t f2bf(float f) {
  uint_t u = __float_as_uint(f);
  uint_t r = (u + 0x7fffu + ((u >> 16) & 1u)) >> 16;
  return (ushort_t)r;
}
__device__ inline float bflo(uint_t u) { return __uint_as_float(u << 16); }
__device__ inline float bfhi(uint_t u) { return __uint_as_float(u & 0xffff0000u); }

// fp8 e4m3: encode 4 floats -> one u32 using ONLY op_sel=false (low-word) ops
__device__ inline uint_t pk4_fp8(float a0, float a1, float a2, float a3) {
  a0 = fminf(fmaxf(a0, -448.f), 448.f);
  a1 = fminf(fmaxf(a1, -448.f), 448.f);
  a2 = fminf(fmaxf(a2, -448.f), 448.f);
  a3 = fminf(fmaxf(a3, -448.f), 448.f);
  uint_t lo = (uint_t)__builtin_amdgcn_cvt_pk_fp8_f32(a0, a1, 0, false) & 0xFFFFu;
  uint_t hi = (uint_t)__builtin_amdgcn_cvt_pk_fp8_f32(a2, a3, 0, false) & 0xFFFFu;
  return lo | (hi << 16);
}

__device__ inline void wave_sync() {
  asm volatile("s_waitcnt lgkmcnt(0)" ::: "memory");
  __builtin_amdgcn_wave_barrier();
}

// ---------------- prepA: wcomb + zero counts --------------------------------
__global__ __launch_bounds__(256) void k_prepA(const float* __restrict__ Wbeta,
                                               float* __restrict__ wcomb,
                                               int* __restrict__ counts) {
  int b = blockIdx.x;
  int o = threadIdx.x;
  if (b == 0) {
    if (o < 128) {
      wcomb[o]       = Wbeta[o]       + Wbeta[256 + o];   // w_out
      wcomb[128 + o] = Wbeta[128 + o] - Wbeta[256 + o];   // w_xr
    }
  } else {
    int i = (b - 1) * 256 + o;
    if (i < NN) counts[i] = 0;
  }
}

// ---------------- prepB: Wbt[512][128] bf16 + bcat + WebT bf16 + hist -------
// Col map: [0,128)=q ; [128,256)=k ; [256,384)=v ; [384,512)=skip
__global__ __launch_bounds__(256) void k_prepB(
    const float* __restrict__ Wq, const float* __restrict__ Wk,
    const float* __restrict__ Wv, const float* __restrict__ Ws,
    const float* __restrict__ bq, const float* __restrict__ bk,
    const float* __restrict__ bv, const float* __restrict__ bs,
    ushort_t* __restrict__ Wbt, float* __restrict__ bcat,
    const float* __restrict__ We, ushort_t* __restrict__ WebT,
    const int* __restrict__ ei, int* __restrict__ counts) {
  int b = blockIdx.x;
  if (b >= 288) {
    int i = (b - 288) * 256 + threadIdx.x;
    if (i < EE) atomicAdd(&counts[ei[EE + i]], 1);
    return;
  }
  if (b >= 256) {
    int i = (b - 256) * 256 + threadIdx.x;   // 0..8191
    int c = i >> 6, k = i & 63;
    WebT[c * 64 + k] = f2bf(We[k * 128 + c]);  // [col][k]
    return;
  }
  int i = b * 256 + threadIdx.x;   // 0..65535
  int c = i >> 7, k = i & 127;
  float w;
  if (c < 128)      w = Wq[k * 128 + c];
  else if (c < 256) w = Wk[k * 128 + (c - 128)];
  else if (c < 384) w = Wv[k * 128 + (c - 256)];
  else              w = Ws[k * 128 + (c - 384)];
  Wbt[(size_t)c * 128 + k] = f2bf(w);
  if (i < 512) {
    float bb;
    if (i < 128)      bb = bq[i];
    else if (i < 256) bb = bk[i - 128];
    else if (i < 384) bb = bv[i - 256];
    else              bb = bs[i - 384];
    bcat[i] = bb;
  }
}

// ---------------- MFMA GEMM: [N,128] @ [128,512] + bias ---------------------
// cb: 0=q->nqx[0:128) f32, 128=k->kb bf16, 256=v->vb bf16, 384=xr->nqx[128:256) f32
__global__ __launch_bounds__(256) void k_mm(const float* __restrict__ x,
                                            const ushort_t* __restrict__ Wbt,
                                            const float* __restrict__ bcat,
                                            float* __restrict__ nqx,
                                            ushort_t* __restrict__ kb,
                                            ushort_t* __restrict__ vb) {
  __shared__ ushort_t As[128 * 128];
  __shared__ ushort_t Bs[128 * 128];
  int t = threadIdx.x;
  int rb = blockIdx.x * 128;
  int cb = blockIdx.y * 128;

  for (int q = t; q < 2048; q += 256) {
    int r = q >> 4, j = q & 15;
    int row = rb + r;
    float4 f0 = make_float4(0.f, 0.f, 0.f, 0.f), f1 = f0;
    if (row < NN) {
      const float4* xp = (const float4*)&x[(size_t)row * 128 + j * 8];
      f0 = xp[0]; f1 = xp[1];
    }
    uint_t u0 = (uint_t)f2bf(f0.x) | ((uint_t)f2bf(f0.y) << 16);
    uint_t u1 = (uint_t)f2bf(f0.z) | ((uint_t)f2bf(f0.w) << 16);
    uint_t u2 = (uint_t)f2bf(f1.x) | ((uint_t)f2bf(f1.y) << 16);
    uint_t u3 = (uint_t)f2bf(f1.z) | ((uint_t)f2bf(f1.w) << 16);
    int e = r * 128 + ((j * 8) ^ ((r & 7) << 3));
    *(uint4*)&As[e] = make_uint4(u0, u1, u2, u3);
  }
  for (int q = t; q < 2048; q += 256) {
    int c = q >> 4, j = q & 15;
    uint4 w = *(const uint4*)&Wbt[(size_t)(cb + c) * 128 + j * 8];
    int e = c * 128 + ((j * 8) ^ ((c & 7) << 3));
    *(uint4*)&Bs[e] = w;
  }
  __syncthreads();

  int lane = t & 63;
  int wv = t >> 6;
  int wr = wv >> 1, wc = wv & 1;
  int l15 = lane & 15, l4 = lane >> 4;

  f32x4 acc[4][4];
#pragma unroll
  for (int i = 0; i < 4; ++i)
#pragma unroll
    for (int j = 0; j < 4; ++j) acc[i][j] = (f32x4){0.f, 0.f, 0.f, 0.f};

#pragma unroll
  for (int ks = 0; ks < 4; ++ks) {
    int kbv = ks * 32 + l4 * 8;
    bf16x8 af[4], bfr[4];
#pragma unroll
    for (int i = 0; i < 4; ++i) {
      int r = wr * 64 + i * 16 + l15;
      af[i] = *(const bf16x8*)&As[r * 128 + (kbv ^ ((r & 7) << 3))];
    }
#pragma unroll
    for (int j = 0; j < 4; ++j) {
      int c = wc * 64 + j * 16 + l15;
      bfr[j] = *(const bf16x8*)&Bs[c * 128 + (kbv ^ ((c & 7) << 3))];
    }
#pragma unroll
    for (int i = 0; i < 4; ++i)
#pragma unroll
      for (int j = 0; j < 4; ++j)
        acc[i][j] = __builtin_amdgcn_mfma_f32_16x16x32_bf16(af[i], bfr[j], acc[i][j], 0, 0, 0);
  }

#pragma unroll
  for (int j = 0; j < 4; ++j) {
    int colg = cb + wc * 64 + j * 16 + l15;
    float bv = bcat[colg];
#pragma unroll
    for (int i = 0; i < 4; ++i) {
#pragma unroll
      for (int reg = 0; reg < 4; ++reg) {
        int grow = rb + wr * 64 + i * 16 + l4 * 4 + reg;
        if (grow < NN) {
          float val = acc[i][j][reg] + bv;
          if (cb == 0)        nqx[(size_t)grow * 256 + colg] = val;
          else if (cb == 128) kb[(size_t)grow * 128 + (colg - 128)] = f2bf(val);
          else if (cb == 256) vb[(size_t)grow * 128 + (colg - 256)] = f2bf(val);
          else                nqx[(size_t)grow * 256 + (colg - 256)] = val;
        }
      }
    }
  }
}

// ---------------- single-block scan, int4-vectorized ------------------------
__global__ __launch_bounds__(1024) void k_scan(int* __restrict__ counts, int* __restrict__ offsets) {
  __shared__ int wsum[16];
  __shared__ int s_carry;
  int4* counts4 = (int4*)counts;
  int4* offsets4 = (int4*)offsets;
  int t = threadIdx.x, lane = t & 63, w = t >> 6;
  if (t == 0) s_carry = 0;
  __syncthreads();
  for (int base = 0; base < 12500; base += 1024) {
    int idx = base + t;
    int4 v = (idx < 12500) ? counts4[idx] : make_int4(0, 0, 0, 0);
    int e1 = v.x, e2 = e1 + v.y, e3 = e2 + v.z, tot = e3 + v.w;
    int s = tot;
#pragma unroll
    for (int off = 1; off < 64; off <<= 1) {
      int u = __shfl_up(s, off);
      if (lane >= off) s += u;
    }
    if (lane == 63) wsum[w] = s;
    __syncthreads();
    if (t == 0) {
      int ex = s_carry;
#pragma unroll
      for (int i = 0; i < 16; ++i) { int tv = wsum[i]; wsum[i] = ex; ex += tv; }
      s_carry = ex;
    }
    __syncthreads();
    int be = wsum[w] + s - tot;
    if (idx < 12500) {
      int4 o = make_int4(be, be + e1, be + e2, be + e3);
      offsets4[idx] = o;
      counts4[idx] = o;
    }
    __syncthreads();
  }
  if (t == 0) offsets[NN] = s_carry;
}

// ---------------- fillw: CSR fill + eW = ea@We (MFMA) -> fp8, CSR order -----
// block = 64 edges; output eaWperm[p][128] fp8 e4m3
__global__ __launch_bounds__(256) void k_fillw(const int* __restrict__ ei,
                                               int* __restrict__ cursors,
                                               const float* __restrict__ ea,
                                               const ushort_t* __restrict__ WebT,
                                               int* __restrict__ srcs,
                                               unsigned char* __restrict__ eaWperm) {
  __shared__ ushort_t As[64 * 64];     // ea tile bf16, swizzled (8KB)
  __shared__ ushort_t Bs[128 * 64];    // WebT bf16, swizzled (16KB)
  __shared__ float Ds[64][68];         // D half-tile f32 (17.4KB)
  __shared__ int sP[64];
  int t = threadIdx.x;
  int eb = blockIdx.x * 64;            // 12500*64 == EE

  if (t < 64) {
    int e = eb + t;
    int d = ei[EE + e];
    int p = atomicAdd(&cursors[d], 1);
    sP[t] = p;
    srcs[p] = ei[e];
  }
  // stage A (ea f32 -> bf16)
  for (int q = t; q < 512; q += 256) {
    int r = q >> 3, j = q & 7;
    const float4* xp = (const float4*)&ea[(size_t)(eb + r) * 64 + j * 8];
    float4 f0 = xp[0], f1 = xp[1];
    uint_t u0 = (uint_t)f2bf(f0.x) | ((uint_t)f2bf(f0.y) << 16);
    uint_t u1 = (uint_t)f2bf(f0.z) | ((uint_t)f2bf(f0.w) << 16);
    uint_t u2 = (uint_t)f2bf(f1.x) | ((uint_t)f2bf(f1.y) << 16);
    uint_t u3 = (uint_t)f2bf(f1.z) | ((uint_t)f2bf(f1.w) << 16);
    *(uint4*)&As[r * 64 + ((j * 8) ^ ((r & 7) << 3))] = make_uint4(u0, u1, u2, u3);
  }
  // stage B (WebT bf16)
  for (int q = t; q < 1024; q += 256) {
    int c = q >> 3, j = q & 7;
    uint4 w = *(const uint4*)&WebT[(size_t)c * 64 + j * 8];
    *(uint4*)&Bs[c * 64 + ((j * 8) ^ ((c & 7) << 3))] = w;
  }
  __syncthreads();

  int lane = t & 63, wv = t >> 6;
  int l15 = lane & 15, l4 = lane >> 4;
  f32x4 acc[4][2];
#pragma unroll
  for (int i = 0; i < 4; ++i)
#pragma unroll
    for (int j = 0; j < 2; ++j) acc[i][j] = (f32x4){0.f, 0.f, 0.f, 0.f};

#pragma unroll
  for (int ks = 0; ks < 2; ++ks) {
    int kbv = ks * 32 + l4 * 8;
    bf16x8 af[4], bfr[2];
#pragma unroll
    for (int i = 0; i < 4; ++i) {
      int r = i * 16 + l15;
      af[i] = *(const bf16x8*)&As[r * 64 + (kbv ^ ((r & 7) << 3))];
    }
#pragma unroll
    for (int j = 0; j < 2; ++j) {
      int c = wv * 32 + j * 16 + l15;
      bfr[j] = *(const bf16x8*)&Bs[c * 64 + (kbv ^ ((c & 7) << 3))];
    }
#pragma unroll
    for (int i = 0; i < 4; ++i)
#pragma unroll
      for (int j = 0; j < 2; ++j)
        acc[i][j] = __builtin_amdgcn_mfma_f32_16x16x32_bf16(af[i], bfr[j], acc[i][j], 0, 0, 0);
  }

  // two column-halves through Ds -> fp8 -> scattered row writes
#pragma unroll
  for (int half = 0; half < 2; ++half) {
    __syncthreads();
    if ((wv >> 1) == half) {
      int cbl = (wv & 1) * 32;
#pragma unroll
      for (int i = 0; i < 4; ++i)
#pragma unroll
        for (int j = 0; j < 2; ++j)
#pragma unroll
          for (int r = 0; r < 4; ++r)
            Ds[i * 16 + l4 * 4 + r][cbl + j * 16 + l15] = acc[i][j][r];
    }
    __syncthreads();
    int edge = t >> 2, seg = t & 3;
    const float* dr = &Ds[edge][seg * 16];
    uint_t wo[4];
#pragma unroll
    for (int i = 0; i < 4; ++i)
      wo[i] = pk4_fp8(dr[4 * i + 0], dr[4 * i + 1], dr[4 * i + 2], dr[4 * i + 3]);
    int p = sP[edge];
    *(uint4*)&eaWperm[(size_t)p * 128 + half * 64 + seg * 16] =
        make_uint4(wo[0], wo[1], wo[2], wo[3]);
  }
}

// ---------------- fused attention + beta-gate + gelu + residual + LN --------
// 1 wave = 1 dst node. lane l: h=l>>4 (head), m=l&15 (edge slot).
// z = q.(k[src]+e), out = sum a*(v[src]+e); e = fp8 eW row.
__global__ __launch_bounds__(256) void k_attn(
    const float* __restrict__ nqx,
    const ushort_t* __restrict__ kb, const ushort_t* __restrict__ vb,
    const unsigned char* __restrict__ eaWperm,
    const int* __restrict__ offsets, const int* __restrict__ srcs,
    const float* __restrict__ x, const float* __restrict__ wcomb,
    const float* __restrict__ gamma, const float* __restrict__ beta_ln,
    float* __restrict__ out) {
  __shared__ float sQ[4][128];
  __shared__ unsigned char sEA[4][16][144];  // 128 fp8 + 16 pad
  __shared__ float sA[4][64];
  __shared__ int   sS[4][16];

  int t = threadIdx.x, wv = t >> 6, l = t & 63;
  int n = blockIdx.x * 4 + wv;
  int h = l >> 4, m = l & 15;
  int c0 = 2 * l, c1 = c0 + 1;
  const float scale = 0.17677669529663687f;   // 1/sqrt(32)

  const float* nrow = nqx + (size_t)n * 256;
  float2 q2 = *(const float2*)&nrow[c0];
  *(float2*)&sQ[wv][c0] = make_float2(q2.x * scale, q2.y * scale);
  if (l < 16) sS[wv][l] = 0;

  int js = offsets[n], je = offsets[n + 1];
  float acc0 = 0.f, acc1 = 0.f, lsum = 0.f;

  for (int base = js; base < je; base += 16) {
    int nj = je - base; if (nj > 16) nj = 16;
    wave_sync();   // prior chunk's LDS readers done; prologue writes visible

    uint4 e0 = {0,0,0,0}, e1 = {0,0,0,0};
    uint4 k0 = {0,0,0,0}, k1 = {0,0,0,0}, k2 = {0,0,0,0}, k3 = {0,0,0,0};
    if (m < nj) {
      int s = srcs[base + m];
      const uint4* erow = (const uint4*)(eaWperm + (size_t)(base + m) * 128 + 32 * h);
      e0 = erow[0]; e1 = erow[1];
      const uint4* krow = (const uint4*)(kb + (size_t)s * 128 + 32 * h);
      k0 = krow[0]; k1 = krow[1]; k2 = krow[2]; k3 = krow[3];
      if (h == 0) sS[wv][m] = s;
    }
    // UNCONDITIONAL: tail rows (m>=nj) get zeros so phase-B's 0*e reads can
    // never decode stale-LDS NaN bytes (the R6/R7 bug: 0*NaN = NaN).
    *(uint4*)&sEA[wv][m][32 * h]      = e0;
    *(uint4*)&sEA[wv][m][32 * h + 16] = e1;
    wave_sync();

    // ---- score z = q.(k+e) over this head's 32 channels ----
    float z = 0.f;
    {
      const float* qp = &sQ[wv][32 * h];
      uint_t eu[8] = {e0.x, e0.y, e0.z, e0.w, e1.x, e1.y, e1.z, e1.w};
      uint_t ku[16] = {k0.x, k0.y, k0.z, k0.w, k1.x, k1.y, k1.z, k1.w,
                       k2.x, k2.y, k2.z, k2.w, k3.x, k3.y, k3.z, k3.w};
#pragma unroll
      for (int u = 0; u < 8; ++u) {
        f32x2 elo = __builtin_amdgcn_cvt_pk_f32_fp8(eu[u] & 0xFFFFu, false);
        f32x2 ehi = __builtin_amdgcn_cvt_pk_f32_fp8(eu[u] >> 16, false);
        float4 q4 = *(const float4*)&qp[4 * u];
        z += q4.x * (bflo(ku[2 * u]) + elo.x)
           + q4.y * (bfhi(ku[2 * u]) + elo.y)
           + q4.z * (bflo(ku[2 * u + 1]) + ehi.x)
           + q4.w * (bfhi(ku[2 * u + 1]) + ehi.y);
      }
    }
    float a = (m < nj) ? __expf(z) : 0.0f;
    lsum += a;
    sA[wv][l] = a;
    wave_sync();

    // ---- phase B: out += a*(v+e) at this lane's 2 channels ----
    {
      int4 s0 = *(const int4*)&sS[wv][0];
      int4 s1 = *(const int4*)&sS[wv][4];
      f32x4 a0 = *(const f32x4*)&sA[wv][16 * h];
      f32x4 a1 = *(const f32x4*)&sA[wv][16 * h + 4];
      uint_t vv[8];
      int sidx[8] = {s0.x, s0.y, s0.z, s0.w, s1.x, s1.y, s1.z, s1.w};
#pragma unroll
      for (int e = 0; e < 8; ++e)
        vv[e] = *(const uint_t*)(vb + (size_t)sidx[e] * 128 + c0);
#pragma unroll
      for (int e = 0; e < 8; ++e) {
        float ae = (e < 4) ? a0[e] : a1[e - 4];
        uint_t ew = (uint_t)*(const ushort_t*)&sEA[wv][e][2 * l];
        f32x2 ef = __builtin_amdgcn_cvt_pk_f32_fp8(ew, false);
        acc0 += ae * (bflo(vv[e]) + ef.x);
        acc1 += ae * (bfhi(vv[e]) + ef.y);
      }
    }
    if (nj > 8) {
      int4 s2 = *(const int4*)&sS[wv][8];
      int4 s3 = *(const int4*)&sS[wv][12];
      f32x4 a2 = *(const f32x4*)&sA[wv][16 * h + 8];
      f32x4 a3 = *(const f32x4*)&sA[wv][16 * h + 12];
      uint_t vv[8];
      int sidx[8] = {s2.x, s2.y, s2.z, s2.w, s3.x, s3.y, s3.z, s3.w};
#pragma unroll
      for (int e = 0; e < 8; ++e)
        vv[e] = *(const uint_t*)(vb + (size_t)sidx[e] * 128 + c0);
#pragma unroll
      for (int e = 0; e < 8; ++e) {
        float ae = (e < 4) ? a2[e] : a3[e - 4];
        uint_t ew = (uint_t)*(const ushort_t*)&sEA[wv][8 + e][2 * l];
        f32x2 ef = __builtin_amdgcn_cvt_pk_f32_fp8(ew, false);
        acc0 += ae * (bflo(vv[e]) + ef.x);
        acc1 += ae * (bfhi(vv[e]) + ef.y);
      }
    }
  }

  // ---- epilogue ----
  lsum += __shfl_xor(lsum, 1); lsum += __shfl_xor(lsum, 2);
  lsum += __shfl_xor(lsum, 4); lsum += __shfl_xor(lsum, 8);

  float inv = (lsum > 0.f) ? (1.0f / lsum) : 1.0f;
  float o0 = acc0 * inv;
  float o1 = acc1 * inv;

  float2 xrv = *(const float2*)&nrow[128 + c0];
  float bp = o0 * wcomb[c0] + o1 * wcomb[c1] + xrv.x * wcomb[128 + c0] + xrv.y * wcomb[128 + c1];
#pragma unroll
  for (int off = 32; off > 0; off >>= 1) bp += __shfl_xor(bp, off);
  float bgate = 1.0f / (1.0f + __expf(-bp));
  float r0 = bgate * xrv.x + (1.0f - bgate) * o0;
  float r1 = bgate * xrv.y + (1.0f - bgate) * o1;

  float2 xv = *(const float2*)&x[(size_t)n * 128 + c0];
  float ge0 = 0.5f * r0 * (1.0f + erff(r0 * 0.70710678118654752f)) + xv.x;
  float ge1 = 0.5f * r1 * (1.0f + erff(r1 * 0.70710678118654752f)) + xv.y;

  float s1 = ge0 + ge1;
  float s2 = ge0 * ge0 + ge1 * ge1;
#pragma unroll
  for (int off = 32; off > 0; off >>= 1) {
    s1 += __shfl_xor(s1, off);
    s2 += __shfl_xor(s2, off);
  }
  float mean = s1 * (1.0f / 128.0f);
  float var = s2 * (1.0f / 128.0f) - mean * mean;
  float rstd = rsqrtf(var + 1e-5f);
  float2 ov;
  ov.x = (ge0 - mean) * rstd * gamma[c0] + beta_ln[c0];
  ov.y = (ge1 - mean) * rstd * gamma[c1] + beta_ln[c1];
  *(float2*)&out[(size_t)n * 128 + c0] = ov;
}

// ---------------- launch ----------------
extern "C" void kernel_launch(void* const* d_in, const int* in_sizes, int n_in,
                              void* d_out, int out_size, void* d_ws, size_t ws_size,
                              hipStream_t stream) {
  const float* x   = (const float*)d_in[0];
  const int*   ei  = (const int*)d_in[1];
  const float* ea  = (const float*)d_in[2];
  const float* Wq  = (const float*)d_in[3];
  const float* bq  = (const float*)d_in[4];
  const float* Wk  = (const float*)d_in[5];
  const float* bk  = (const float*)d_in[6];
  const float* Wv  = (const float*)d_in[7];
  const float* bv  = (const float*)d_in[8];
  const float* We  = (const float*)d_in[9];
  const float* Wsk = (const float*)d_in[10];
  const float* bsk = (const float*)d_in[11];
  const float* Wb  = (const float*)d_in[12];
  const float* gamma = (const float*)d_in[13];
  const float* beta  = (const float*)d_in[14];
  float* out = (float*)d_out;

  char* cur = (char*)d_ws;
  auto alloc = [&](size_t bytes) {
    void* p = (void*)cur;
    cur += (bytes + 255) & ~(size_t)255;
    return p;
  };
  float*         nqx     = (float*)alloc((size_t)NN * 256 * 4);     // q | xr (f32)
  ushort_t*      kbuf    = (ushort_t*)alloc((size_t)NN * 128 * 2);
  ushort_t*      vbuf    = (ushort_t*)alloc((size_t)NN * 128 * 2);
  unsigned char* eaWperm = (unsigned char*)alloc((size_t)EE * 128); // fp8 eW, CSR order
  int*           srcs    = (int*)alloc((size_t)EE * 4);
  float*         wcomb   = (float*)alloc(256 * 4);
  float*         bcat    = (float*)alloc(512 * 4);
  ushort_t*      Wbt     = (ushort_t*)alloc((size_t)512 * 128 * 2);
  ushort_t*      WebT    = (ushort_t*)alloc((size_t)128 * 64 * 2);
  int*           counts  = (int*)alloc((size_t)NN * 4);
  int*           offsets = (int*)alloc((size_t)(NN + 4) * 4);

  k_prepA<<<197, 256, 0, stream>>>(Wb, wcomb, counts);
  k_prepB<<<288 + 3125, 256, 0, stream>>>(Wq, Wk, Wv, Wsk, bq, bk, bv, bsk,
                                          Wbt, bcat, We, WebT, ei, counts);
  k_mm<<<dim3(391, 4), 256, 0, stream>>>(x, Wbt, bcat, nqx, kbuf, vbuf);
  k_scan<<<1, 1024, 0, stream>>>(counts, offsets);
  k_fillw<<<12500, 256, 0, stream>>>(ei, counts, ea, WebT, srcs, eaWperm);
  k_attn<<<12500, 256, 0, stream>>>(nqx, kbuf, vbuf, eaWperm, offsets, srcs,
                                    x, wcomb, gamma, beta, out);
}

// Round 9
// 311.095 us; speedup vs baseline: 3.0200x; 1.0719x over previous
//
#include <hip/hip_runtime.h>
#include <math.h>

#define NN 50000
#define EE 800000
// D=128, H=4, C=32, ED=64

typedef __bf16 bf16x8 __attribute__((ext_vector_type(8)));
typedef float f32x4 __attribute__((ext_vector_type(4)));
typedef float f32x2 __attribute__((ext_vector_type(2)));
typedef unsigned short ushort_t;
typedef unsigned int uint_t;

__device__ inline ushort_t f2bf(float f) {
  uint_t u = __float_as_uint(f);
  uint_t r = (u + 0x7fffu + ((u >> 16) & 1u)) >> 16;
  return (ushort_t)r;
}
__device__ inline float bflo(uint_t u) { return __uint_as_float(u << 16); }
__device__ inline float bfhi(uint_t u) { return __uint_as_float(u & 0xffff0000u); }

// fp8 e4m3: encode 4 floats -> one u32 using ONLY op_sel=false (low-word) ops
__device__ inline uint_t pk4_fp8(float a0, float a1, float a2, float a3) {
  a0 = fminf(fmaxf(a0, -448.f), 448.f);
  a1 = fminf(fmaxf(a1, -448.f), 448.f);
  a2 = fminf(fmaxf(a2, -448.f), 448.f);
  a3 = fminf(fmaxf(a3, -448.f), 448.f);
  uint_t lo = (uint_t)__builtin_amdgcn_cvt_pk_fp8_f32(a0, a1, 0, false) & 0xFFFFu;
  uint_t hi = (uint_t)__builtin_amdgcn_cvt_pk_fp8_f32(a2, a3, 0, false) & 0xFFFFu;
  return lo | (hi << 16);
}

__device__ inline void wave_sync() {
  asm volatile("s_waitcnt lgkmcnt(0)" ::: "memory");
  __builtin_amdgcn_wave_barrier();
}

// ---------------- prepA: wcomb + zero counts --------------------------------
__global__ __launch_bounds__(256) void k_prepA(const float* __restrict__ Wbeta,
                                               float* __restrict__ wcomb,
                                               int* __restrict__ counts) {
  int b = blockIdx.x;
  int o = threadIdx.x;
  if (b == 0) {
    if (o < 128) {
      wcomb[o]       = Wbeta[o]       + Wbeta[256 + o];   // w_out
      wcomb[128 + o] = Wbeta[128 + o] - Wbeta[256 + o];   // w_xr
    }
  } else {
    int i = (b - 1) * 256 + o;
    if (i < NN) counts[i] = 0;
  }
}

// ---------------- prepB: Wbt[512][128] bf16 + bcat + WebT bf16 + hist -------
// Col map: [0,128)=q ; [128,256)=k ; [256,384)=v ; [384,512)=skip
__global__ __launch_bounds__(256) void k_prepB(
    const float* __restrict__ Wq, const float* __restrict__ Wk,
    const float* __restrict__ Wv, const float* __restrict__ Ws,
    const float* __restrict__ bq, const float* __restrict__ bk,
    const float* __restrict__ bv, const float* __restrict__ bs,
    ushort_t* __restrict__ Wbt, float* __restrict__ bcat,
    const float* __restrict__ We, ushort_t* __restrict__ WebT,
    const int* __restrict__ ei, int* __restrict__ counts) {
  int b = blockIdx.x;
  if (b >= 288) {
    int i = (b - 288) * 256 + threadIdx.x;
    if (i < EE) atomicAdd(&counts[ei[EE + i]], 1);
    return;
  }
  if (b >= 256) {
    int i = (b - 256) * 256 + threadIdx.x;   // 0..8191
    int c = i >> 6, k = i & 63;
    WebT[c * 64 + k] = f2bf(We[k * 128 + c]);  // [col][k]
    return;
  }
  int i = b * 256 + threadIdx.x;   // 0..65535
  int c = i >> 7, k = i & 127;
  float w;
  if (c < 128)      w = Wq[k * 128 + c];
  else if (c < 256) w = Wk[k * 128 + (c - 128)];
  else if (c < 384) w = Wv[k * 128 + (c - 256)];
  else              w = Ws[k * 128 + (c - 384)];
  Wbt[(size_t)c * 128 + k] = f2bf(w);
  if (i < 512) {
    float bb;
    if (i < 128)      bb = bq[i];
    else if (i < 256) bb = bk[i - 128];
    else if (i < 384) bb = bv[i - 256];
    else              bb = bs[i - 384];
    bcat[i] = bb;
  }
}

// ---------------- MFMA GEMM: [N,128] @ [128,512] + bias ---------------------
// cb: 0=q->nqx[0:128) f32, 128=k->kb bf16, 256=v->vb bf16, 384=xr->nqx[128:256) f32
__global__ __launch_bounds__(256) void k_mm(const float* __restrict__ x,
                                            const ushort_t* __restrict__ Wbt,
                                            const float* __restrict__ bcat,
                                            float* __restrict__ nqx,
                                            ushort_t* __restrict__ kb,
                                            ushort_t* __restrict__ vb) {
  __shared__ ushort_t As[128 * 128];
  __shared__ ushort_t Bs[128 * 128];
  int t = threadIdx.x;
  int rb = blockIdx.x * 128;
  int cb = blockIdx.y * 128;

  for (int q = t; q < 2048; q += 256) {
    int r = q >> 4, j = q & 15;
    int row = rb + r;
    float4 f0 = make_float4(0.f, 0.f, 0.f, 0.f), f1 = f0;
    if (row < NN) {
      const float4* xp = (const float4*)&x[(size_t)row * 128 + j * 8];
      f0 = xp[0]; f1 = xp[1];
    }
    uint_t u0 = (uint_t)f2bf(f0.x) | ((uint_t)f2bf(f0.y) << 16);
    uint_t u1 = (uint_t)f2bf(f0.z) | ((uint_t)f2bf(f0.w) << 16);
    uint_t u2 = (uint_t)f2bf(f1.x) | ((uint_t)f2bf(f1.y) << 16);
    uint_t u3 = (uint_t)f2bf(f1.z) | ((uint_t)f2bf(f1.w) << 16);
    int e = r * 128 + ((j * 8) ^ ((r & 7) << 3));
    *(uint4*)&As[e] = make_uint4(u0, u1, u2, u3);
  }
  for (int q = t; q < 2048; q += 256) {
    int c = q >> 4, j = q & 15;
    uint4 w = *(const uint4*)&Wbt[(size_t)(cb + c) * 128 + j * 8];
    int e = c * 128 + ((j * 8) ^ ((c & 7) << 3));
    *(uint4*)&Bs[e] = w;
  }
  __syncthreads();

  int lane = t & 63;
  int wv = t >> 6;
  int wr = wv >> 1, wc = wv & 1;
  int l15 = lane & 15, l4 = lane >> 4;

  f32x4 acc[4][4];
#pragma unroll
  for (int i = 0; i < 4; ++i)
#pragma unroll
    for (int j = 0; j < 4; ++j) acc[i][j] = (f32x4){0.f, 0.f, 0.f, 0.f};

#pragma unroll
  for (int ks = 0; ks < 4; ++ks) {
    int kbv = ks * 32 + l4 * 8;
    bf16x8 af[4], bfr[4];
#pragma unroll
    for (int i = 0; i < 4; ++i) {
      int r = wr * 64 + i * 16 + l15;
      af[i] = *(const bf16x8*)&As[r * 128 + (kbv ^ ((r & 7) << 3))];
    }
#pragma unroll
    for (int j = 0; j < 4; ++j) {
      int c = wc * 64 + j * 16 + l15;
      bfr[j] = *(const bf16x8*)&Bs[c * 128 + (kbv ^ ((c & 7) << 3))];
    }
#pragma unroll
    for (int i = 0; i < 4; ++i)
#pragma unroll
      for (int j = 0; j < 4; ++j)
        acc[i][j] = __builtin_amdgcn_mfma_f32_16x16x32_bf16(af[i], bfr[j], acc[i][j], 0, 0, 0);
  }

#pragma unroll
  for (int j = 0; j < 4; ++j) {
    int colg = cb + wc * 64 + j * 16 + l15;
    float bv = bcat[colg];
#pragma unroll
    for (int i = 0; i < 4; ++i) {
#pragma unroll
      for (int reg = 0; reg < 4; ++reg) {
        int grow = rb + wr * 64 + i * 16 + l4 * 4 + reg;
        if (grow < NN) {
          float val = acc[i][j][reg] + bv;
          if (cb == 0)        nqx[(size_t)grow * 256 + colg] = val;
          else if (cb == 128) kb[(size_t)grow * 128 + (colg - 128)] = f2bf(val);
          else if (cb == 256) vb[(size_t)grow * 128 + (colg - 256)] = f2bf(val);
          else                nqx[(size_t)grow * 256 + (colg - 256)] = val;
        }
      }
    }
  }
}

// ---------------- single-block scan, int4-vectorized ------------------------
__global__ __launch_bounds__(1024) void k_scan(int* __restrict__ counts, int* __restrict__ offsets) {
  __shared__ int wsum[16];
  __shared__ int s_carry;
  int4* counts4 = (int4*)counts;
  int4* offsets4 = (int4*)offsets;
  int t = threadIdx.x, lane = t & 63, w = t >> 6;
  if (t == 0) s_carry = 0;
  __syncthreads();
  for (int base = 0; base < 12500; base += 1024) {
    int idx = base + t;
    int4 v = (idx < 12500) ? counts4[idx] : make_int4(0, 0, 0, 0);
    int e1 = v.x, e2 = e1 + v.y, e3 = e2 + v.z, tot = e3 + v.w;
    int s = tot;
#pragma unroll
    for (int off = 1; off < 64; off <<= 1) {
      int u = __shfl_up(s, off);
      if (lane >= off) s += u;
    }
    if (lane == 63) wsum[w] = s;
    __syncthreads();
    if (t == 0) {
      int ex = s_carry;
#pragma unroll
      for (int i = 0; i < 16; ++i) { int tv = wsum[i]; wsum[i] = ex; ex += tv; }
      s_carry = ex;
    }
    __syncthreads();
    int be = wsum[w] + s - tot;
    if (idx < 12500) {
      int4 o = make_int4(be, be + e1, be + e2, be + e3);
      offsets4[idx] = o;
      counts4[idx] = o;
    }
    __syncthreads();
  }
  if (t == 0) offsets[NN] = s_carry;
}

// ---------------- fillw: CSR fill + eW^T = WebT @ ea^T (MFMA) -> fp8 --------
// block = 64 edges. Transposed GEMM: D[row=eW channel][col=edge], so each lane
// owns 4 CONSECUTIVE channels of one edge per fragment -> pk4_fp8 -> one u32.
// fp8 bytes staged into As' own 8KB region (64 edges x 128B exactly); safe:
// each wave reads (bfr hoist) and writes only its own 16 As rows.
__global__ __launch_bounds__(256) void k_fillw(const int* __restrict__ ei,
                                               int* __restrict__ cursors,
                                               const float* __restrict__ ea,
                                               const ushort_t* __restrict__ WebT,
                                               int* __restrict__ srcs,
                                               unsigned char* __restrict__ eaWperm) {
  __shared__ ushort_t As[64 * 64];     // ea tile bf16 swizzled; later fp8 out tile (8KB)
  __shared__ ushort_t Bs[128 * 64];    // WebT bf16 swizzled (16KB)
  __shared__ int sP[64];
  int t = threadIdx.x;
  int eb = blockIdx.x * 64;            // 12500*64 == EE

  if (t < 64) {
    int e = eb + t;
    int d = ei[EE + e];
    int p = atomicAdd(&cursors[d], 1);
    sP[t] = p;
    srcs[p] = ei[e];
  }
  // stage A (ea f32 -> bf16)
  for (int q = t; q < 512; q += 256) {
    int r = q >> 3, j = q & 7;
    const float4* xp = (const float4*)&ea[(size_t)(eb + r) * 64 + j * 8];
    float4 f0 = xp[0], f1 = xp[1];
    uint_t u0 = (uint_t)f2bf(f0.x) | ((uint_t)f2bf(f0.y) << 16);
    uint_t u1 = (uint_t)f2bf(f0.z) | ((uint_t)f2bf(f0.w) << 16);
    uint_t u2 = (uint_t)f2bf(f1.x) | ((uint_t)f2bf(f1.y) << 16);
    uint_t u3 = (uint_t)f2bf(f1.z) | ((uint_t)f2bf(f1.w) << 16);
    *(uint4*)&As[r * 64 + ((j * 8) ^ ((r & 7) << 3))] = make_uint4(u0, u1, u2, u3);
  }
  // stage B (WebT bf16)
  for (int q = t; q < 1024; q += 256) {
    int c = q >> 3, j = q & 7;
    uint4 w = *(const uint4*)&WebT[(size_t)c * 64 + j * 8];
    *(uint4*)&Bs[c * 64 + ((j * 8) ^ ((c & 7) << 3))] = w;
  }
  __syncthreads();

  int lane = t & 63, wv = t >> 6;
  int l15 = lane & 15, l4 = lane >> 4;
  int edge = wv * 16 + l15;            // this lane's edge (B-operand column)

  // hoist B-frags (ea fragments) to registers BEFORE As is overwritten
  bf16x8 bfr[2];
#pragma unroll
  for (int ks = 0; ks < 2; ++ks) {
    int kbv = ks * 32 + l4 * 8;
    bfr[ks] = *(const bf16x8*)&As[edge * 64 + (kbv ^ ((edge & 7) << 3))];
  }

  f32x4 acc[8];
#pragma unroll
  for (int i = 0; i < 8; ++i) acc[i] = (f32x4){0.f, 0.f, 0.f, 0.f};

#pragma unroll
  for (int ks = 0; ks < 2; ++ks) {
    int kbv = ks * 32 + l4 * 8;
#pragma unroll
    for (int i = 0; i < 8; ++i) {
      int c = i * 16 + l15;            // A row = eW channel
      bf16x8 af = *(const bf16x8*)&Bs[c * 64 + (kbv ^ ((c & 7) << 3))];
      acc[i] = __builtin_amdgcn_mfma_f32_16x16x32_bf16(af, bfr[ks], acc[i], 0, 0, 0);
    }
  }

  // pack: lane owns channels i*16 + l4*4 + {0..3} of `edge`
  wave_sync();   // all lanes of this wave done reading their As rows
  uint_t* dst32 = (uint_t*)As;         // alias: edge*128 bytes -> edge*32 u32
#pragma unroll
  for (int i = 0; i < 8; ++i)
    dst32[edge * 32 + i * 4 + l4] = pk4_fp8(acc[i][0], acc[i][1], acc[i][2], acc[i][3]);
  wave_sync();   // lgkmcnt drain: cross-lane (same wave) readback below

  // write out: wave's 16 edges x 128B; lane -> (edge_local = lane>>2, seg = lane&3)
  int el = wv * 16 + (lane >> 2), seg = lane & 3;
  const uint4* srow = (const uint4*)((const unsigned char*)As + el * 128 + seg * 16);
  uint4 lo = srow[0];
  uint4 hi = srow[4];                  // +64 bytes
  int p = sP[el];
  *(uint4*)&eaWperm[(size_t)p * 128 + seg * 16]      = lo;
  *(uint4*)&eaWperm[(size_t)p * 128 + seg * 16 + 64] = hi;
}

// ---------------- fused attention + beta-gate + gelu + residual + LN --------
// 1 wave = 1 dst node. lane l: h=l>>4 (head), m=l&15 (edge slot).
// z = q.(k[src]+e), out = sum a*(v[src]+e); e = fp8 eW row.
__global__ __launch_bounds__(256) void k_attn(
    const float* __restrict__ nqx,
    const ushort_t* __restrict__ kb, const ushort_t* __restrict__ vb,
    const unsigned char* __restrict__ eaWperm,
    const int* __restrict__ offsets, const int* __restrict__ srcs,
    const float* __restrict__ x, const float* __restrict__ wcomb,
    const float* __restrict__ gamma, const float* __restrict__ beta_ln,
    float* __restrict__ out) {
  __shared__ float sQ[4][128];
  __shared__ unsigned char sEA[4][16][144];  // 128 fp8 + 16 pad
  __shared__ float sA[4][64];
  __shared__ int   sS[4][16];

  int t = threadIdx.x, wv = t >> 6, l = t & 63;
  int n = blockIdx.x * 4 + wv;
  int h = l >> 4, m = l & 15;
  int c0 = 2 * l, c1 = c0 + 1;
  const float scale = 0.17677669529663687f;   // 1/sqrt(32)

  const float* nrow = nqx + (size_t)n * 256;
  float2 q2 = *(const float2*)&nrow[c0];
  *(float2*)&sQ[wv][c0] = make_float2(q2.x * scale, q2.y * scale);
  if (l < 16) sS[wv][l] = 0;

  int js = offsets[n], je = offsets[n + 1];
  float acc0 = 0.f, acc1 = 0.f, lsum = 0.f;

  for (int base = js; base < je; base += 16) {
    int nj = je - base; if (nj > 16) nj = 16;
    wave_sync();   // prior chunk's LDS readers done; prologue writes visible

    uint4 e0 = {0,0,0,0}, e1 = {0,0,0,0};
    uint4 k0 = {0,0,0,0}, k1 = {0,0,0,0}, k2 = {0,0,0,0}, k3 = {0,0,0,0};
    if (m < nj) {
      int s = srcs[base + m];
      const uint4* erow = (const uint4*)(eaWperm + (size_t)(base + m) * 128 + 32 * h);
      e0 = erow[0]; e1 = erow[1];
      const uint4* krow = (const uint4*)(kb + (size_t)s * 128 + 32 * h);
      k0 = krow[0]; k1 = krow[1]; k2 = krow[2]; k3 = krow[3];
      if (h == 0) sS[wv][m] = s;
    }
    // UNCONDITIONAL: tail rows (m>=nj) get zeros so phase-B's 0*e reads can
    // never decode stale-LDS NaN bytes (the R6/R7 bug: 0*NaN = NaN).
    *(uint4*)&sEA[wv][m][32 * h]      = e0;
    *(uint4*)&sEA[wv][m][32 * h + 16] = e1;
    wave_sync();

    // ---- score z = q.(k+e) over this head's 32 channels ----
    float z = 0.f;
    {
      const float* qp = &sQ[wv][32 * h];
      uint_t eu[8] = {e0.x, e0.y, e0.z, e0.w, e1.x, e1.y, e1.z, e1.w};
      uint_t ku[16] = {k0.x, k0.y, k0.z, k0.w, k1.x, k1.y, k1.z, k1.w,
                       k2.x, k2.y, k2.z, k2.w, k3.x, k3.y, k3.z, k3.w};
#pragma unroll
      for (int u = 0; u < 8; ++u) {
        f32x2 elo = __builtin_amdgcn_cvt_pk_f32_fp8(eu[u] & 0xFFFFu, false);
        f32x2 ehi = __builtin_amdgcn_cvt_pk_f32_fp8(eu[u] >> 16, false);
        float4 q4 = *(const float4*)&qp[4 * u];
        z += q4.x * (bflo(ku[2 * u]) + elo.x)
           + q4.y * (bfhi(ku[2 * u]) + elo.y)
           + q4.z * (bflo(ku[2 * u + 1]) + ehi.x)
           + q4.w * (bfhi(ku[2 * u + 1]) + ehi.y);
      }
    }
    float a = (m < nj) ? __expf(z) : 0.0f;
    lsum += a;
    sA[wv][l] = a;
    wave_sync();

    // ---- phase B: out += a*(v+e) at this lane's 2 channels ----
    {
      int4 s0 = *(const int4*)&sS[wv][0];
      int4 s1 = *(const int4*)&sS[wv][4];
      f32x4 a0 = *(const f32x4*)&sA[wv][16 * h];
      f32x4 a1 = *(const f32x4*)&sA[wv][16 * h + 4];
      uint_t vv[8];
      int sidx[8] = {s0.x, s0.y, s0.z, s0.w, s1.x, s1.y, s1.z, s1.w};
#pragma unroll
      for (int e = 0; e < 8; ++e)
        vv[e] = *(const uint_t*)(vb + (size_t)sidx[e] * 128 + c0);
#pragma unroll
      for (int e = 0; e < 8; ++e) {
        float ae = (e < 4) ? a0[e] : a1[e - 4];
        uint_t ew = (uint_t)*(const ushort_t*)&sEA[wv][e][2 * l];
        f32x2 ef = __builtin_amdgcn_cvt_pk_f32_fp8(ew, false);
        acc0 += ae * (bflo(vv[e]) + ef.x);
        acc1 += ae * (bfhi(vv[e]) + ef.y);
      }
    }
    if (nj > 8) {
      int4 s2 = *(const int4*)&sS[wv][8];
      int4 s3 = *(const int4*)&sS[wv][12];
      f32x4 a2 = *(const f32x4*)&sA[wv][16 * h + 8];
      f32x4 a3 = *(const f32x4*)&sA[wv][16 * h + 12];
      uint_t vv[8];
      int sidx[8] = {s2.x, s2.y, s2.z, s2.w, s3.x, s3.y, s3.z, s3.w};
#pragma unroll
      for (int e = 0; e < 8; ++e)
        vv[e] = *(const uint_t*)(vb + (size_t)sidx[e] * 128 + c0);
#pragma unroll
      for (int e = 0; e < 8; ++e) {
        float ae = (e < 4) ? a2[e] : a3[e - 4];
        uint_t ew = (uint_t)*(const ushort_t*)&sEA[wv][8 + e][2 * l];
        f32x2 ef = __builtin_amdgcn_cvt_pk_f32_fp8(ew, false);
        acc0 += ae * (bflo(vv[e]) + ef.x);
        acc1 += ae * (bfhi(vv[e]) + ef.y);
      }
    }
  }

  // ---- epilogue ----
  lsum += __shfl_xor(lsum, 1); lsum += __shfl_xor(lsum, 2);
  lsum += __shfl_xor(lsum, 4); lsum += __shfl_xor(lsum, 8);

  float inv = (lsum > 0.f) ? (1.0f / lsum) : 1.0f;
  float o0 = acc0 * inv;
  float o1 = acc1 * inv;

  float2 xrv = *(const float2*)&nrow[128 + c0];
  float bp = o0 * wcomb[c0] + o1 * wcomb[c1] + xrv.x * wcomb[128 + c0] + xrv.y * wcomb[128 + c1];
#pragma unroll
  for (int off = 32; off > 0; off >>= 1) bp += __shfl_xor(bp, off);
  float bgate = 1.0f / (1.0f + __expf(-bp));
  float r0 = bgate * xrv.x + (1.0f - bgate) * o0;
  float r1 = bgate * xrv.y + (1.0f - bgate) * o1;

  float2 xv = *(const float2*)&x[(size_t)n * 128 + c0];
  float ge0 = 0.5f * r0 * (1.0f + erff(r0 * 0.70710678118654752f)) + xv.x;
  float ge1 = 0.5f * r1 * (1.0f + erff(r1 * 0.70710678118654752f)) + xv.y;

  float s1 = ge0 + ge1;
  float s2 = ge0 * ge0 + ge1 * ge1;
#pragma unroll
  for (int off = 32; off > 0; off >>= 1) {
    s1 += __shfl_xor(s1, off);
    s2 += __shfl_xor(s2, off);
  }
  float mean = s1 * (1.0f / 128.0f);
  float var = s2 * (1.0f / 128.0f) - mean * mean;
  float rstd = rsqrtf(var + 1e-5f);
  float2 ov;
  ov.x = (ge0 - mean) * rstd * gamma[c0] + beta_ln[c0];
  ov.y = (ge1 - mean) * rstd * gamma[c1] + beta_ln[c1];
  *(float2*)&out[(size_t)n * 128 + c0] = ov;
}

// ---------------- launch ----------------
extern "C" void kernel_launch(void* const* d_in, const int* in_sizes, int n_in,
                              void* d_out, int out_size, void* d_ws, size_t ws_size,
                              hipStream_t stream) {
  const float* x   = (const float*)d_in[0];
  const int*   ei  = (const int*)d_in[1];
  const float* ea  = (const float*)d_in[2];
  const float* Wq  = (const float*)d_in[3];
  const float* bq  = (const float*)d_in[4];
  const float* Wk  = (const float*)d_in[5];
  const float* bk  = (const float*)d_in[6];
  const float* Wv  = (const float*)d_in[7];
  const float* bv  = (const float*)d_in[8];
  const float* We  = (const float*)d_in[9];
  const float* Wsk = (const float*)d_in[10];
  const float* bsk = (const float*)d_in[11];
  const float* Wb  = (const float*)d_in[12];
  const float* gamma = (const float*)d_in[13];
  const float* beta  = (const float*)d_in[14];
  float* out = (float*)d_out;

  char* cur = (char*)d_ws;
  auto alloc = [&](size_t bytes) {
    void* p = (void*)cur;
    cur += (bytes + 255) & ~(size_t)255;
    return p;
  };
  float*         nqx     = (float*)alloc((size_t)NN * 256 * 4);     // q | xr (f32)
  ushort_t*      kbuf    = (ushort_t*)alloc((size_t)NN * 128 * 2);
  ushort_t*      vbuf    = (ushort_t*)alloc((size_t)NN * 128 * 2);
  unsigned char* eaWperm = (unsigned char*)alloc((size_t)EE * 128); // fp8 eW, CSR order
  int*           srcs    = (int*)alloc((size_t)EE * 4);
  float*         wcomb   = (float*)alloc(256 * 4);
  float*         bcat    = (float*)alloc(512 * 4);
  ushort_t*      Wbt     = (ushort_t*)alloc((size_t)512 * 128 * 2);
  ushort_t*      WebT    = (ushort_t*)alloc((size_t)128 * 64 * 2);
  int*           counts  = (int*)alloc((size_t)NN * 4);
  int*           offsets = (int*)alloc((size_t)(NN + 4) * 4);

  k_prepA<<<197, 256, 0, stream>>>(Wb, wcomb, counts);
  k_prepB<<<288 + 3125, 256, 0, stream>>>(Wq, Wk, Wv, Wsk, bq, bk, bv, bsk,
                                          Wbt, bcat, We, WebT, ei, counts);
  k_mm<<<dim3(391, 4), 256, 0, stream>>>(x, Wbt, bcat, nqx, kbuf, vbuf);
  k_scan<<<1, 1024, 0, stream>>>(counts, offsets);
  k_fillw<<<12500, 256, 0, stream>>>(ei, counts, ea, WebT, srcs, eaWperm);
  k_attn<<<12500, 256, 0, stream>>>(nqx, kbuf, vbuf, eaWperm, offsets, srcs,
                                    x, wcomb, gamma, beta, out);
}